// Round 5
// baseline (576.375 us; speedup 1.0000x reference)
//
#include <hip/hip_runtime.h>
#include <hip/hip_bf16.h>

// GraphVertEdgeNet on MI355X. B=64, N=64, VF=32, EF=16, DV=DE=128, LN=4.
// e stored bf16 in ws (64MB) in TRANSPOSED layout e_t[b][j][i][c].
// Round-5: keep round-4's fusion (v-update + BN stats inside edge kernels;
// -5 dispatches worth ~110us) and fix its cost: every matvec previously
// loaded weights W[k][c] at stride-512B (serial ~15us latency chain per
// block, fully exposed in the fused tails). k_prep now pre-transposes all
// matvec weights to Wt[c][k] (f32, exact) so each thread streams its own
// contiguous weight row with pipelined float4 loads (chain ~17.5us -> ~3us).

typedef __bf16 bf16_t;
typedef __bf16 bf16x8 __attribute__((ext_vector_type(8)));
typedef __bf16 bf16x4 __attribute__((ext_vector_type(4)));
typedef float f32x4 __attribute__((ext_vector_type(4)));

// Barrier that does NOT drain vmcnt: safe when cross-wave deps are LDS-only.
__device__ __forceinline__ void bar_lgkm() {
  asm volatile("s_waitcnt lgkmcnt(0)\n\ts_barrier" ::: "memory");
}

// ---------------- prep: input BN (v0), all weight transposes, zero stats ----------------
__global__ __launch_bounds__(256) void k_prep(const float* __restrict__ vin,
    const float* __restrict__ g, const float* __restrict__ bt,
    const float* __restrict__ eW, const float* __restrict__ inn_vW,
    const float* __restrict__ g1_vW, const float* __restrict__ inn_evW,
    const float* __restrict__ g1_evW, float* __restrict__ v0,
    bf16_t* __restrict__ Wt, float* __restrict__ stats,
    float* __restrict__ vWt, float* __restrict__ g1_vWt,
    float* __restrict__ evWt, float* __restrict__ g1_evWt) {
  const int blk = blockIdx.x, tid = threadIdx.x;
  if (blk < 8) {  // BatchNorm1d(N*VF) over batch, ch = 0..2047
    int ch = blk * 256 + tid;
    float s = 0.f, s2 = 0.f;
    for (int b = 0; b < 64; ++b) { float x = vin[b * 2048 + ch]; s += x; s2 += x * x; }
    float mu = s * (1.f / 64.f);
    float var = s2 * (1.f / 64.f) - mu * mu;  // biased var
    float sc = rsqrtf(var + 1e-5f) * g[ch];
    float bb = bt[ch];
    for (int b = 0; b < 64; ++b) {
      float x = vin[b * 2048 + ch];
      v0[b * 2048 + ch] = (x - mu) * sc + bb;
    }
  } else if (blk < 264) {  // Wt[l][n][k] = eW[l][k][n] as bf16 (MFMA operand)
    int idx = (blk - 8) * 256 + tid;  // 4*128*128 = 65536
    int l = idx >> 14, r = idx & 16383, n = r >> 7, k = r & 127;
    Wt[idx] = (bf16_t)eW[(l << 14) + (k << 7) + n];
  } else if (blk == 264) {  // zero stats (512 f32)
    for (int i = tid; i < 512; i += 256) stats[i] = 0.f;
  } else if (blk < 777) {  // vWt[l][c][k=256] = inn_vW[l][k][c]
    int idx = (blk - 265) * 256 + tid;  // 131072
    int l = idx >> 15, r = idx & 32767, c = r >> 8, k = r & 255;
    vWt[idx] = inn_vW[(l << 15) + (k << 7) + c];
  } else if (blk < 857) {  // g1_vWt[c][k=160] = g1_vW[k][c]
    int idx = (blk - 777) * 256 + tid;  // 20480
    int c = idx / 160, k = idx - c * 160;
    g1_vWt[idx] = g1_vW[k * 128 + c];
  } else if (blk < 1113) {  // evWt[l][c][k=128] = inn_evW[l][k][c]
    int idx = (blk - 857) * 256 + tid;  // 65536
    int l = idx >> 14, r = idx & 16383, c = r >> 7, k = r & 127;
    evWt[idx] = inn_evW[(l << 14) + (k << 7) + c];
  } else {  // g1_evWt[c][k=32] = g1_evW[k][c]
    int idx = (blk - 1113) * 256 + tid;  // 4096
    int c = idx >> 5, k = idx & 31;
    g1_evWt[idx] = g1_evW[(k << 7) + c];
  }
}

// ------------- ev = v_in @ W + bias via transposed weights Wt_[c][K]. 8 rows/blk -------------
template <int K>
__global__ __launch_bounds__(256) void k_ev(const float* __restrict__ v_in,
    const float* __restrict__ Wt_, const float* __restrict__ bias,
    float* __restrict__ out) {
  __shared__ float rows_s[8][K];
  const int r0 = blockIdx.x * 8;
  const int tid = threadIdx.x;
  const int c = tid & 127, h = tid >> 7;  // h: rows h*4 .. h*4+3
  for (int idx = tid; idx < 8 * K; idx += 256) {
    int rr = idx / K, kk = idx % K;
    rows_s[rr][kk] = v_in[(r0 + rr) * K + kk];
  }
  __syncthreads();
  float acc[4];
  const float bv = bias[c];
#pragma unroll
  for (int r = 0; r < 4; ++r) acc[r] = bv;
#pragma unroll 8
  for (int k4 = 0; k4 < K; k4 += 4) {
    float4 wv = *(const float4*)&Wt_[c * K + k4];
#pragma unroll
    for (int r = 0; r < 4; ++r) {
      float4 x = *(const float4*)&rows_s[h * 4 + r][k4];
      acc[r] += x.x * wv.x + x.y * wv.y + x.z * wv.z + x.w * wv.w;
    }
  }
#pragma unroll
  for (int r = 0; r < 4; ++r) out[(r0 + h * 4 + r) * 128 + c] = acc[r];
}

// ------------- fused BN(prev) + ev matmul (transposed weights). 8 rows/blk -------------
__global__ __launch_bounds__(256) void k_evbn(float* __restrict__ v,
    const float* __restrict__ stats, const float* __restrict__ g,
    const float* __restrict__ bt, const float* __restrict__ Wt_,
    const float* __restrict__ bias, float* __restrict__ out) {
  __shared__ float rows_s[8][128];
  const int r0 = blockIdx.x * 8;
  const int tid = threadIdx.x;
  const int c = tid & 127, h = tid >> 7;
#pragma unroll
  for (int u = 0; u < 4; ++u) {
    int idx = u * 256 + tid;
    int rr = idx >> 7, k = idx & 127;
    int n = (r0 + rr) & 63;
    float mu = stats[n] * (1.f / 8192.f);
    float var = stats[64 + n] * (1.f / 8192.f) - mu * mu;
    float sc = rsqrtf(var + 128.f) * g[n];
    float x = (v[(r0 + rr) * 128 + k] - mu) * sc + bt[n];
    rows_s[rr][k] = x;
    v[(r0 + rr) * 128 + k] = x;  // normalized v for residual/concat
  }
  __syncthreads();
  float acc[4];
  const float bv = bias[c];
#pragma unroll
  for (int r = 0; r < 4; ++r) acc[r] = bv;
#pragma unroll 8
  for (int k4 = 0; k4 < 128; k4 += 4) {
    float4 wv = *(const float4*)&Wt_[c * 128 + k4];
#pragma unroll
    for (int r = 0; r < 4; ++r) {
      float4 x = *(const float4*)&rows_s[h * 4 + r][k4];
      acc[r] += x.x * wv.x + x.y * wv.y + x.z * wv.z + x.w * wv.w;
    }
  }
#pragma unroll
  for (int r = 0; r < 4; ++r) out[(r0 + h * 4 + r) * 128 + c] = acc[r];
}

// ------------- g1 edge pass (MFMA, K 16->32 zero-pad, 2 j/block) + fused g1-v + ev0 ------
// Writes e_t[b][j][i][c] (transposed layout), v rows j0..j0+1, ev0 rows j0..j0+1.
__global__ __launch_bounds__(256) void k_edge_g1(const float* __restrict__ e0,
    const float* __restrict__ eW, const float* __restrict__ eb,
    const float* __restrict__ evA, bf16_t* __restrict__ e_ws,
    const float* __restrict__ v0, const float* __restrict__ vWt_,
    const float* __restrict__ vb, const float* __restrict__ evWt0,
    const float* __restrict__ evb, float* __restrict__ v,
    float* __restrict__ evB) {
  __shared__ bf16_t A0s[2][64][40];
  __shared__ bf16_t Os[2][64][136];
  __shared__ float in_s[2][160];  // [jc][ pve(128) | v0row(32) ]
  __shared__ float vr_s[2][128];
  const int b = blockIdx.x >> 5, j0 = (blockIdx.x & 31) * 2;
  const int tid = threadIdx.x;
  const int lane = tid & 63, w = tid >> 6;
  const int quad = lane >> 4, l16 = lane & 15;
  f32x4 v0reg;
  if (tid < 16)
    v0reg = *(const f32x4*)&v0[(b * 64 + j0 + (tid >> 3)) * 32 + (tid & 7) * 4];
#pragma unroll
  for (int t = 0; t < 2; ++t) {
    int idx = tid + t * 256;
    int row = idx >> 3, off = (idx & 7) * 4;
    int jc = off >> 4, k = off & 15;
    f32x4 x = *(const f32x4*)&e0[((b * 64 + row) * 64 + j0) * 16 + off];
    bf16x4 y;
#pragma unroll
    for (int r = 0; r < 4; ++r) y[r] = (bf16_t)x[r];
    *(bf16x4*)&A0s[jc][row][k] = y;
    bf16x4 z = {(bf16_t)0.f, (bf16_t)0.f, (bf16_t)0.f, (bf16_t)0.f};
    *(bf16x4*)&A0s[jc][row][16 + k] = z;
  }
  const int c0[2] = {w * 32 + quad * 4, w * 32 + 16 + quad * 4};
  bf16x8 wf[2];
#pragma unroll
  for (int nt = 0; nt < 2; ++nt) {
    const int c = w * 32 + nt * 16 + l16;
#pragma unroll
    for (int jj = 0; jj < 8; ++jj)
      wf[nt][jj] = (quad < 2) ? (bf16_t)eW[(quad * 8 + jj) * 128 + c] : (bf16_t)0.f;
  }
  f32x4 acc[2][4][2];
  {
    f32x4 ebv[2], evj[2][2], evi[4][2];
#pragma unroll
    for (int nt = 0; nt < 2; ++nt) {
      ebv[nt] = *(const f32x4*)&eb[c0[nt]];
#pragma unroll
      for (int jc = 0; jc < 2; ++jc)
        evj[jc][nt] = *(const f32x4*)&evA[(b * 64 + j0 + jc) * 128 + c0[nt]];
#pragma unroll
      for (int mt = 0; mt < 4; ++mt)
        evi[mt][nt] = *(const f32x4*)&evA[(b * 64 + mt * 16 + l16) * 128 + c0[nt]];
    }
#pragma unroll
    for (int jc = 0; jc < 2; ++jc)
#pragma unroll
      for (int mt = 0; mt < 4; ++mt)
#pragma unroll
        for (int nt = 0; nt < 2; ++nt)
          acc[jc][mt][nt] = ebv[nt] + evj[jc][nt] + evi[mt][nt];
  }
  __syncthreads();
#pragma unroll
  for (int jc = 0; jc < 2; ++jc) {
#pragma unroll
    for (int mt = 0; mt < 4; ++mt) {
      bf16x8 ef = *(const bf16x8*)&A0s[jc][mt * 16 + l16][quad * 8];
#pragma unroll
      for (int nt = 0; nt < 2; ++nt)
        acc[jc][mt][nt] = __builtin_amdgcn_mfma_f32_16x16x32_bf16(wf[nt], ef, acc[jc][mt][nt], 0, 0, 0);
    }
  }
#pragma unroll
  for (int jc = 0; jc < 2; ++jc) {
#pragma unroll
    for (int nt = 0; nt < 2; ++nt) {
      f32x4 ps = {0.f, 0.f, 0.f, 0.f};
#pragma unroll
      for (int mt = 0; mt < 4; ++mt) {
        const int i = mt * 16 + l16;
        bf16x4 outv;
#pragma unroll
        for (int r = 0; r < 4; ++r) {
          float vv = fmaxf(acc[jc][mt][nt][r], 0.f);
          ps[r] += vv;
          outv[r] = (bf16_t)vv;
        }
        *(bf16x4*)&Os[jc][i][c0[nt]] = outv;
      }
#pragma unroll
      for (int m = 1; m <= 8; m <<= 1) {
#pragma unroll
        for (int r = 0; r < 4; ++r) ps[r] += __shfl_xor(ps[r], m);
      }
      if (l16 == 0) *(f32x4*)&in_s[jc][c0[nt]] = ps;  // pve -> LDS
    }
  }
  if (tid < 16) *(f32x4*)&in_s[tid >> 3][128 + (tid & 7) * 4] = v0reg;
  __syncthreads();
  {  // contiguous 32KB copy-out to transposed layout
    bf16_t* ebase = &e_ws[((size_t)(b * 64 + j0) * 64) * 128];
#pragma unroll
    for (int t = 0; t < 8; ++t) {
      int idx = tid + t * 256;
      *(int4*)&ebase[idx * 8] =
          *(const int4*)&Os[idx >> 10][(idx >> 4) & 63][(idx & 15) * 8];
    }
  }
  // fused g1-v: v = relu(concat(pve, v0)@vW + vb), row-local, float4 weight rows
  const int c = tid & 127, h = tid >> 7;
  float vacc = vb[c];
#pragma unroll 8
  for (int k4 = 0; k4 < 160; k4 += 4) {
    float4 wv = *(const float4*)&vWt_[c * 160 + k4];
    float4 x = *(const float4*)&in_s[h][k4];
    vacc += x.x * wv.x + x.y * wv.y + x.z * wv.z + x.w * wv.w;
  }
  float vr = fmaxf(vacc, 0.f);
  v[(b * 64 + j0 + h) * 128 + c] = vr;
  vr_s[h][c] = vr;
  __syncthreads();
  // fused layer-0 ev: evB = v @ evW + evb, row-local
  float acc2 = evb[c];
#pragma unroll 8
  for (int k4 = 0; k4 < 128; k4 += 4) {
    float4 wv = *(const float4*)&evWt0[c * 128 + k4];
    float4 x = *(const float4*)&vr_s[h][k4];
    acc2 += x.x * wv.x + x.y * wv.y + x.z * wv.z + x.w * wv.w;
  }
  evB[(b * 64 + j0 + h) * 128 + c] = acc2;
}

// ------------- inner edge pass + fused v-update & BN stats ------------------------
// e_t[b][j][i][c]: block (b,j0) owns a contiguous 32KB region AND v rows j0..j0+1.
// e += relu(e@W + eb + ev_i + ev_j); pve (pre-residual col sums) stays in LDS;
// v = relu(concat(pve,v)@vW + vb) + v; BN stats atomically accumulated.
// LAST: e write-back replaced by edot[b][j][i] = dot(e_new[b,i,j,:], eW3).
template <bool LAST>
__global__ __launch_bounds__(256) void k_edge_inner(bf16_t* __restrict__ e_ws,
    const bf16_t* __restrict__ Wt, const float* __restrict__ eb,
    const float* __restrict__ ev, const float* __restrict__ eW3,
    float* __restrict__ edt, float* __restrict__ v,
    const float* __restrict__ vWt_, const float* __restrict__ vb,
    float* __restrict__ stats) {
  __shared__ bf16_t As[2][64][136];   // [jc][i][c], +8 pad
  __shared__ float W3s[128];
  __shared__ float in_s[2][256];      // [jc][ pve(128) | vrow(128) ]
  __shared__ float part[4][2];
  const int b = blockIdx.x >> 5, j0 = (blockIdx.x & 31) * 2;
  const int tid = threadIdx.x;
  const int lane = tid & 63, w = tid >> 6;
  const int quad = lane >> 4, l16 = lane & 15;
  bf16_t* ebase = &e_ws[((size_t)(b * 64 + j0) * 64) * 128];
  // stage 2 e columns: one contiguous 32KB stream
  int4 stg[8];
#pragma unroll
  for (int t = 0; t < 8; ++t) {
    int idx = tid + t * 256;
    stg[t] = *(const int4*)&ebase[idx * 8];
  }
  f32x4 vreg;
  if (tid < 64)
    vreg = *(const f32x4*)&v[(b * 64 + j0 + (tid >> 5)) * 128 + (tid & 31) * 4];
  if (LAST) {
    if (tid < 128) W3s[tid] = eW3[tid];
  }
  // W A-frags in registers (L2-hot): A[m=c][k]
  bf16x8 wf[2][4];
#pragma unroll
  for (int nt = 0; nt < 2; ++nt)
#pragma unroll
    for (int ks = 0; ks < 4; ++ks)
      wf[nt][ks] = *(const bf16x8*)&Wt[(w * 32 + nt * 16 + l16) * 128 + ks * 32 + quad * 8];
  const int c0[2] = {w * 32 + quad * 4, w * 32 + 16 + quad * 4};
  // acc init = eb + ev_j + ev_i (pre-barrier loads)
  f32x4 acc[2][4][2];
  {
    f32x4 ebv[2], evj[2][2], evi[4][2];
#pragma unroll
    for (int nt = 0; nt < 2; ++nt) {
      ebv[nt] = *(const f32x4*)&eb[c0[nt]];
#pragma unroll
      for (int jc = 0; jc < 2; ++jc)
        evj[jc][nt] = *(const f32x4*)&ev[(b * 64 + j0 + jc) * 128 + c0[nt]];
#pragma unroll
      for (int mt = 0; mt < 4; ++mt)
        evi[mt][nt] = *(const f32x4*)&ev[(b * 64 + mt * 16 + l16) * 128 + c0[nt]];
    }
#pragma unroll
    for (int jc = 0; jc < 2; ++jc)
#pragma unroll
      for (int mt = 0; mt < 4; ++mt)
#pragma unroll
        for (int nt = 0; nt < 2; ++nt)
          acc[jc][mt][nt] = ebv[nt] + evj[jc][nt] + evi[mt][nt];
  }
#pragma unroll
  for (int t = 0; t < 8; ++t) {
    int idx = tid + t * 256;
    *(int4*)&As[idx >> 10][(idx >> 4) & 63][(idx & 15) * 8] = stg[t];
  }
  bar_lgkm();
  // MFMA: D[c][i] = sum_k Wt[c][k] * e[i][k]  (64 MFMA per block)
#pragma unroll
  for (int ks = 0; ks < 4; ++ks) {
    bf16x8 ef[2][4];
#pragma unroll
    for (int jc = 0; jc < 2; ++jc)
#pragma unroll
      for (int mt = 0; mt < 4; ++mt)
        ef[jc][mt] = *(const bf16x8*)&As[jc][mt * 16 + l16][ks * 32 + quad * 8];
#pragma unroll
    for (int jc = 0; jc < 2; ++jc)
#pragma unroll
      for (int mt = 0; mt < 4; ++mt)
#pragma unroll
        for (int nt = 0; nt < 2; ++nt)
          acc[jc][mt][nt] = __builtin_amdgcn_mfma_f32_16x16x32_bf16(wf[nt][ks], ef[jc][mt], acc[jc][mt][nt], 0, 0, 0);
  }
  bar_lgkm();  // all MFMA frag reads of As done (LDS-only dep)
  // epilogue: relu, pve->LDS, residual from LDS, packed writes to own cells
#pragma unroll
  for (int jc = 0; jc < 2; ++jc) {
#pragma unroll
    for (int nt = 0; nt < 2; ++nt) {
      f32x4 ps = {0.f, 0.f, 0.f, 0.f};
#pragma unroll
      for (int mt = 0; mt < 4; ++mt) {
        const int i = mt * 16 + l16;
        bf16x4 eo = *(const bf16x4*)&As[jc][i][c0[nt]];
        bf16x4 outv;
#pragma unroll
        for (int r = 0; r < 4; ++r) {
          float vv = fmaxf(acc[jc][mt][nt][r], 0.f);
          ps[r] += vv;                            // pve is pre-residual
          outv[r] = (bf16_t)(vv + (float)eo[r]);  // residual
        }
        *(bf16x4*)&As[jc][i][c0[nt]] = outv;
      }
#pragma unroll
      for (int m = 1; m <= 8; m <<= 1) {  // reduce over i (l16 lanes)
#pragma unroll
        for (int r = 0; r < 4; ++r) ps[r] += __shfl_xor(ps[r], m);
      }
      if (l16 == 0) *(f32x4*)&in_s[jc][c0[nt]] = ps;  // pve -> LDS
    }
  }
  if (tid < 64) *(f32x4*)&in_s[tid >> 5][128 + (tid & 31) * 4] = vreg;
  bar_lgkm();  // As + in_s fully updated (LDS-only dep)
  if (!LAST) {
    // contiguous 32KB write-back
#pragma unroll
    for (int t = 0; t < 8; ++t) {
      int idx = tid + t * 256;
      *(int4*)&ebase[idx * 8] =
          *(const int4*)&As[idx >> 10][(idx >> 4) & 63][(idx & 15) * 8];
    }
  } else {
    // edot[b][j][i] = dot(e_new[b,i,j,:], W3)
    const int i = tid >> 2, q = tid & 3;
#pragma unroll
    for (int jc = 0; jc < 2; ++jc) {
      float d = 0.f;
#pragma unroll
      for (int t = 0; t < 4; ++t) {
        bf16x8 x = *(const bf16x8*)&As[jc][i][q * 32 + t * 8];
#pragma unroll
        for (int u = 0; u < 8; ++u) d += (float)x[u] * W3s[q * 32 + t * 8 + u];
      }
      d += __shfl_xor(d, 1);
      d += __shfl_xor(d, 2);
      if (q == 0) edt[(b * 64 + j0 + jc) * 64 + i] = d;
    }
  }
  // fused v-update: v = relu(concat(pve, v)@vW + vb) + v; float4 weight rows
  const int c = tid & 127, h = tid >> 7;
  float vacc = vb[c];
#pragma unroll 8
  for (int k4 = 0; k4 < 256; k4 += 4) {
    float4 wv = *(const float4*)&vWt_[c * 256 + k4];
    float4 x = *(const float4*)&in_s[h][k4];
    vacc += x.x * wv.x + x.y * wv.y + x.z * wv.z + x.w * wv.w;
  }
  float vnew = fmaxf(vacc, 0.f) + in_s[h][128 + c];  // relu + residual
  v[(b * 64 + j0 + h) * 128 + c] = vnew;
  // BN stats: butterfly over each 64-lane wave (one wave = 64 c's of one j)
  float s = vnew, s2 = vnew * vnew;
#pragma unroll
  for (int m = 1; m <= 32; m <<= 1) {
    s += __shfl_xor(s, m);
    s2 += __shfl_xor(s2, m);
  }
  if (lane == 0) { part[w][0] = s; part[w][1] = s2; }
  bar_lgkm();
  if (tid < 2) {
    int n = j0 + tid;
    atomicAdd(&stats[n], part[tid * 2][0] + part[tid * 2 + 1][0]);
    atomicAdd(&stats[64 + n], part[tid * 2][1] + part[tid * 2 + 1][1]);
  }
}

// ------------- g3 final: per-b block. BN(v), ev3, out_e = edot+eb3+ev3_i+ev3_j,
// pve3 in LDS, out_v. One kernel, 64 blocks. -------------
__global__ __launch_bounds__(256) void k_g3(const float* __restrict__ vv,
    const float* __restrict__ stats3, const float* __restrict__ g,
    const float* __restrict__ bt, const float* __restrict__ evW3,
    const float* __restrict__ evb3, const float* __restrict__ eb3,
    const float* __restrict__ edt, const float* __restrict__ vW3,
    const float* __restrict__ vb3, float* __restrict__ out_v,
    float* __restrict__ out_e) {
  __shared__ float vbn[64][132];   // +4 pad
  __shared__ float edts[64][68];   // edt[b][j][i], +4 pad
  __shared__ float scs[64], shs[64];
  __shared__ float W3e[128];
  __shared__ float vWs[132];
  __shared__ float ev3s[64];
  __shared__ float pj[4][64];
  const int b = blockIdx.x, tid = threadIdx.x;
  if (tid < 64) {
    float mu = stats3[tid] * (1.f / 8192.f);
    float var = stats3[64 + tid] * (1.f / 8192.f) - mu * mu;
    float sc = rsqrtf(var + 128.f) * g[tid];
    scs[tid] = sc;
    shs[tid] = bt[tid] - mu * sc;
  }
  if (tid < 128) W3e[tid] = evW3[tid];
  if (tid < 129) vWs[tid] = vW3[tid];
  __syncthreads();
#pragma unroll
  for (int t = 0; t < 8; ++t) {  // stage BN(v[b])
    int idx = t * 1024 + tid * 4;
    int row = idx >> 7, cc = idx & 127;
    f32x4 x = *(const f32x4*)&vv[(b * 64 + row) * 128 + cc];
    *(f32x4*)&vbn[row][cc] = x * scs[row] + shs[row];
  }
#pragma unroll
  for (int t = 0; t < 4; ++t) {  // stage edot[b]
    int idx = t * 1024 + tid * 4;
    int j = idx >> 6, i = idx & 63;
    *(f32x4*)&edts[j][i] = *(const f32x4*)&edt[(b * 64 + j) * 64 + i];
  }
  __syncthreads();
  {  // ev3s[i] = dot(vbn[i], W3e) + evb3
    int i = tid >> 2, q = tid & 3;
    float d = 0.f;
#pragma unroll
    for (int u = 0; u < 32; ++u) d += vbn[i][q * 32 + u] * W3e[q * 32 + u];
    d += __shfl_xor(d, 1);
    d += __shfl_xor(d, 2);
    if (q == 0) ev3s[i] = d + evb3[0];
  }
  __syncthreads();
  {  // out_e + per-j partial sums
    int q = tid >> 6, j = tid & 63;
    float s = 0.f;
    const float e3 = eb3[0];
    const float evj = ev3s[j];
#pragma unroll
    for (int r = 0; r < 16; ++r) {
      int i = q * 16 + r;
      float val = edts[j][i] + e3 + ev3s[i] + evj;
      out_e[(b * 64 + i) * 64 + j] = val;
      s += val;
    }
    pj[q][j] = s;
  }
  __syncthreads();
  {  // out_v[b,n] = pve3*vW[0] + dot(vbn[n], vW[1:129]) + vb
    int n = tid >> 2, q = tid & 3;
    float d = 0.f;
#pragma unroll
    for (int u = 0; u < 32; ++u) d += vbn[n][q * 32 + u] * vWs[1 + q * 32 + u];
    d += __shfl_xor(d, 1);
    d += __shfl_xor(d, 2);
    if (q == 0) {
      float p3 = pj[0][n] + pj[1][n] + pj[2][n] + pj[3][n];
      out_v[b * 64 + n] = d + p3 * vWs[0] + vb3[0];
    }
  }
}

extern "C" void kernel_launch(void* const* d_in, const int* in_sizes, int n_in,
                              void* d_out, int out_size, void* d_ws, size_t ws_size,
                              hipStream_t stream) {
  const float* in_v    = (const float*)d_in[0];
  const float* in_e    = (const float*)d_in[1];
  const float* bn_in_g = (const float*)d_in[2];
  const float* bn_in_b = (const float*)d_in[3];
  const float* g1_evW  = (const float*)d_in[4];
  const float* g1_evb  = (const float*)d_in[5];
  const float* g1_eW   = (const float*)d_in[6];
  const float* g1_eb   = (const float*)d_in[7];
  const float* g1_vW   = (const float*)d_in[8];
  const float* g1_vb   = (const float*)d_in[9];
  const float* inn_evW = (const float*)d_in[10];
  const float* inn_evb = (const float*)d_in[11];
  const float* inn_eW  = (const float*)d_in[12];
  const float* inn_eb  = (const float*)d_in[13];
  const float* inn_vW  = (const float*)d_in[14];
  const float* inn_vb  = (const float*)d_in[15];
  const float* bn_g    = (const float*)d_in[16];
  const float* bn_b    = (const float*)d_in[17];
  const float* g3_evW  = (const float*)d_in[18];
  const float* g3_evb  = (const float*)d_in[19];
  const float* g3_eW   = (const float*)d_in[20];
  const float* g3_eb   = (const float*)d_in[21];
  const float* g3_vW   = (const float*)d_in[22];
  const float* g3_vb   = (const float*)d_in[23];

  char* ws = (char*)d_ws;
  bf16_t* e_ws = (bf16_t*)(ws);                       // 64MB : e_t[b][j][i][c] bf16
  float* v       = (float*)(ws + 67108864);           // 2MB
  float* evA     = (float*)(ws + 69206016);           // 2MB : g1's ev
  float* evB     = (float*)(ws + 71303168);           // 2MB : inner-layer ev
  float* v0      = (float*)(ws + 73400320);           // 512KB
  bf16_t* Wt     = (bf16_t*)(ws + 73924608);          // 128KB (MFMA bf16)
  float* edt     = (float*)(ws + 74055680);           // 1MB : edot[b][j][i]
  float* stats   = (float*)(ws + 75104256);           // 2KB
  float* g1_vWt  = (float*)(ws + 75106304);           // 80KB  [128][160]
  float* vWt     = (float*)(ws + 75188224);           // 512KB [4][128][256]
  float* g1_evWt = (float*)(ws + 75712512);           // 16KB  [128][32]
  float* evWt    = (float*)(ws + 75728896);           // 256KB [4][128][128]

  float* out_v = (float*)d_out;          // [B,N,1] = 4096
  float* out_e = (float*)d_out + 4096;   // [B,N,N,1] = 262144

  k_prep<<<1129, 256, 0, stream>>>(in_v, bn_in_g, bn_in_b, inn_eW, inn_vW, g1_vW,
                                   inn_evW, g1_evW, v0, Wt, stats,
                                   vWt, g1_vWt, evWt, g1_evWt);

  // ---- g1 (edge + fused v + fused layer-0 ev) ----
  k_ev<32><<<512, 256, 0, stream>>>(v0, g1_evWt, g1_evb, evA);
  k_edge_g1<<<2048, 256, 0, stream>>>(in_e, g1_eW, g1_eb, evA, e_ws,
                                      v0, g1_vWt, g1_vb, evWt, inn_evb, v, evB);

  // ---- inner layers: [evbn] -> edge(+v+stats) ----
  for (int l = 0; l < 4; ++l) {
    if (l > 0)
      k_evbn<<<512, 256, 0, stream>>>(v, stats + (l - 1) * 128, bn_g + (l - 1) * 64,
                                      bn_b + (l - 1) * 64, evWt + l * 16384,
                                      inn_evb + l * 128, evB);
    if (l < 3)
      k_edge_inner<false><<<2048, 256, 0, stream>>>(e_ws, Wt + l * 16384,
          inn_eb + l * 128, evB, g3_eW, edt, v,
          vWt + l * 32768, inn_vb + l * 128, stats + l * 128);
    else
      k_edge_inner<true><<<2048, 256, 0, stream>>>(e_ws, Wt + l * 16384,
          inn_eb + l * 128, evB, g3_eW, edt, v,
          vWt + l * 32768, inn_vb + l * 128, stats + l * 128);
  }

  // ---- g3 final (BN of layer 3 on the fly; pve3 in-block) ----
  k_g3<<<64, 256, 0, stream>>>(v, stats + 384, bn_g + 192, bn_b + 192,
                               g3_evW, g3_evb, g3_eb, edt, g3_vW, g3_vb,
                               out_v, out_e);
}

// Round 6
// 376.005 us; speedup vs baseline: 1.5329x; 1.5329x over previous
//
#include <hip/hip_runtime.h>
#include <hip/hip_bf16.h>

// GraphVertEdgeNet on MI355X. B=64, N=64, VF=32, EF=16, DV=DE=128, LN=4.
// e stored bf16 in ws (64MB) in TRANSPOSED layout e_t[b][j][i][c].
// Round-6: round-4 fusion (v-update + BN stats inside edge kernels) with the
// matvec tail fixed the RIGHT way: weights stay in original [k][c] layout
// (lane=c -> coalesced 256B loads; round-5's per-thread rows were 64x
// uncoalesced and a disaster). Redundancy removed by 2-way k-split across
// wave pairs (waves 0,1: k-half 0; waves 2,3: k-half 1; each wave covers 64
// c's for BOTH output rows) -> weight matrix read once per block (128KB not
// 256KB), half the chain length, unroll-4 float4 pipelining, 2KB LDS reduce.
// k_prep/k_ev/k_evbn/k_g3 are the round-0 proven forms.

typedef __bf16 bf16_t;
typedef __bf16 bf16x8 __attribute__((ext_vector_type(8)));
typedef __bf16 bf16x4 __attribute__((ext_vector_type(4)));
typedef float f32x4 __attribute__((ext_vector_type(4)));

// Barrier that does NOT drain vmcnt: safe when cross-wave deps are LDS-only.
__device__ __forceinline__ void bar_lgkm() {
  asm volatile("s_waitcnt lgkmcnt(0)\n\ts_barrier" ::: "memory");
}

// ---------------- prep: input BN (v0), Wt transpose, zero stats ----------------
__global__ __launch_bounds__(256) void k_prep(const float* __restrict__ vin,
    const float* __restrict__ g, const float* __restrict__ bt,
    const float* __restrict__ eW, float* __restrict__ v0,
    bf16_t* __restrict__ Wt, float* __restrict__ stats) {
  const int blk = blockIdx.x, tid = threadIdx.x;
  if (blk < 8) {  // BatchNorm1d(N*VF) over batch, ch = 0..2047
    int ch = blk * 256 + tid;
    float s = 0.f, s2 = 0.f;
    for (int b = 0; b < 64; ++b) { float x = vin[b * 2048 + ch]; s += x; s2 += x * x; }
    float mu = s * (1.f / 64.f);
    float var = s2 * (1.f / 64.f) - mu * mu;  // biased var
    float sc = rsqrtf(var + 1e-5f) * g[ch];
    float bb = bt[ch];
    for (int b = 0; b < 64; ++b) {
      float x = vin[b * 2048 + ch];
      v0[b * 2048 + ch] = (x - mu) * sc + bb;
    }
  } else if (blk < 264) {  // Wt[l][n][k] = eW[l][k][n] as bf16 (MFMA operand)
    int idx = (blk - 8) * 256 + tid;  // 4*128*128 = 65536
    int l = idx >> 14, r = idx & 16383, n = r >> 7, k = r & 127;
    Wt[idx] = (bf16_t)eW[(l << 14) + (k << 7) + n];
  } else {  // zero stats (512 f32)
    for (int i = tid; i < 512; i += 256) stats[i] = 0.f;
  }
}

// ------------- ev = v_in @ W + bias : [4096,K]@[K,128]. 256 thr, 8 rows/blk -------------
template <int K>
__global__ __launch_bounds__(256) void k_ev(const float* __restrict__ v_in,
    const float* __restrict__ W, const float* __restrict__ bias,
    float* __restrict__ out) {
  __shared__ float rows_s[8][K];
  const int r0 = blockIdx.x * 8;
  const int tid = threadIdx.x;
  const int c = tid & 127, h = tid >> 7;  // h: rows h*4 .. h*4+3
  for (int idx = tid; idx < 8 * K; idx += 256) {
    int rr = idx / K, kk = idx % K;
    rows_s[rr][kk] = v_in[(r0 + rr) * K + kk];
  }
  __syncthreads();
  float acc[4];
  const float bv = bias[c];
#pragma unroll
  for (int r = 0; r < 4; ++r) acc[r] = bv;
  for (int k4 = 0; k4 < K; k4 += 4) {
    float w0 = W[(k4 + 0) * 128 + c], w1 = W[(k4 + 1) * 128 + c];
    float w2 = W[(k4 + 2) * 128 + c], w3 = W[(k4 + 3) * 128 + c];
#pragma unroll
    for (int r = 0; r < 4; ++r) {
      float4 x = *(const float4*)&rows_s[h * 4 + r][k4];
      acc[r] += x.x * w0 + x.y * w1 + x.z * w2 + x.w * w3;
    }
  }
#pragma unroll
  for (int r = 0; r < 4; ++r) out[(r0 + h * 4 + r) * 128 + c] = acc[r];
}

// ------------- fused BN(prev) + ev matmul (in-place v normalize). 256 thr -------------
__global__ __launch_bounds__(256) void k_evbn(float* __restrict__ v,
    const float* __restrict__ stats, const float* __restrict__ g,
    const float* __restrict__ bt, const float* __restrict__ W,
    const float* __restrict__ bias, float* __restrict__ out) {
  __shared__ float rows_s[8][128];
  const int r0 = blockIdx.x * 8;
  const int tid = threadIdx.x;
  const int c = tid & 127, h = tid >> 7;
#pragma unroll
  for (int u = 0; u < 4; ++u) {
    int idx = u * 256 + tid;
    int rr = idx >> 7, k = idx & 127;
    int n = (r0 + rr) & 63;
    float mu = stats[n] * (1.f / 8192.f);
    float var = stats[64 + n] * (1.f / 8192.f) - mu * mu;
    float sc = rsqrtf(var + 128.f) * g[n];
    float x = (v[(r0 + rr) * 128 + k] - mu) * sc + bt[n];
    rows_s[rr][k] = x;
    v[(r0 + rr) * 128 + k] = x;  // normalized v for residual/concat
  }
  __syncthreads();
  float acc[4];
  const float bv = bias[c];
#pragma unroll
  for (int r = 0; r < 4; ++r) acc[r] = bv;
  for (int k4 = 0; k4 < 128; k4 += 4) {
    float w0 = W[(k4 + 0) * 128 + c], w1 = W[(k4 + 1) * 128 + c];
    float w2 = W[(k4 + 2) * 128 + c], w3 = W[(k4 + 3) * 128 + c];
#pragma unroll
    for (int r = 0; r < 4; ++r) {
      float4 x = *(const float4*)&rows_s[h * 4 + r][k4];
      acc[r] += x.x * w0 + x.y * w1 + x.z * w2 + x.w * w3;
    }
  }
#pragma unroll
  for (int r = 0; r < 4; ++r) out[(r0 + h * 4 + r) * 128 + c] = acc[r];
}

// ------------- g1 edge pass (MFMA, K 16->32 zero-pad, 2 j/block) + fused g1-v + ev0 ------
// Writes e_t[b][j][i][c] (transposed layout), v rows j0..j0+1, ev0 rows j0..j0+1.
// Tails use 2-way k-split across wave pairs, coalesced W[k][c] loads.
__global__ __launch_bounds__(256) void k_edge_g1(const float* __restrict__ e0,
    const float* __restrict__ eW, const float* __restrict__ eb,
    const float* __restrict__ evA, bf16_t* __restrict__ e_ws,
    const float* __restrict__ v0, const float* __restrict__ vW,
    const float* __restrict__ vb, const float* __restrict__ evW0,
    const float* __restrict__ evb, float* __restrict__ v,
    float* __restrict__ evB) {
  __shared__ bf16_t A0s[2][64][40];
  __shared__ bf16_t Os[2][64][136];
  __shared__ float in_s[2][160];  // [jc][ pve(128) | v0row(32) ]
  __shared__ float vr_s[2][128];
  __shared__ float red[2][2][128];  // [khalf][h][c]
  const int b = blockIdx.x >> 5, j0 = (blockIdx.x & 31) * 2;
  const int tid = threadIdx.x;
  const int lane = tid & 63, w = tid >> 6;
  const int quad = lane >> 4, l16 = lane & 15;
  f32x4 v0reg;
  if (tid < 16)
    v0reg = *(const f32x4*)&v0[(b * 64 + j0 + (tid >> 3)) * 32 + (tid & 7) * 4];
#pragma unroll
  for (int t = 0; t < 2; ++t) {
    int idx = tid + t * 256;
    int row = idx >> 3, off = (idx & 7) * 4;
    int jc = off >> 4, k = off & 15;
    f32x4 x = *(const f32x4*)&e0[((b * 64 + row) * 64 + j0) * 16 + off];
    bf16x4 y;
#pragma unroll
    for (int r = 0; r < 4; ++r) y[r] = (bf16_t)x[r];
    *(bf16x4*)&A0s[jc][row][k] = y;
    bf16x4 z = {(bf16_t)0.f, (bf16_t)0.f, (bf16_t)0.f, (bf16_t)0.f};
    *(bf16x4*)&A0s[jc][row][16 + k] = z;
  }
  const int c0[2] = {w * 32 + quad * 4, w * 32 + 16 + quad * 4};
  bf16x8 wf[2];
#pragma unroll
  for (int nt = 0; nt < 2; ++nt) {
    const int c = w * 32 + nt * 16 + l16;
#pragma unroll
    for (int jj = 0; jj < 8; ++jj)
      wf[nt][jj] = (quad < 2) ? (bf16_t)eW[(quad * 8 + jj) * 128 + c] : (bf16_t)0.f;
  }
  f32x4 acc[2][4][2];
  {
    f32x4 ebv[2], evj[2][2], evi[4][2];
#pragma unroll
    for (int nt = 0; nt < 2; ++nt) {
      ebv[nt] = *(const f32x4*)&eb[c0[nt]];
#pragma unroll
      for (int jc = 0; jc < 2; ++jc)
        evj[jc][nt] = *(const f32x4*)&evA[(b * 64 + j0 + jc) * 128 + c0[nt]];
#pragma unroll
      for (int mt = 0; mt < 4; ++mt)
        evi[mt][nt] = *(const f32x4*)&evA[(b * 64 + mt * 16 + l16) * 128 + c0[nt]];
    }
#pragma unroll
    for (int jc = 0; jc < 2; ++jc)
#pragma unroll
      for (int mt = 0; mt < 4; ++mt)
#pragma unroll
        for (int nt = 0; nt < 2; ++nt)
          acc[jc][mt][nt] = ebv[nt] + evj[jc][nt] + evi[mt][nt];
  }
  __syncthreads();
#pragma unroll
  for (int jc = 0; jc < 2; ++jc) {
#pragma unroll
    for (int mt = 0; mt < 4; ++mt) {
      bf16x8 ef = *(const bf16x8*)&A0s[jc][mt * 16 + l16][quad * 8];
#pragma unroll
      for (int nt = 0; nt < 2; ++nt)
        acc[jc][mt][nt] = __builtin_amdgcn_mfma_f32_16x16x32_bf16(wf[nt], ef, acc[jc][mt][nt], 0, 0, 0);
    }
  }
#pragma unroll
  for (int jc = 0; jc < 2; ++jc) {
#pragma unroll
    for (int nt = 0; nt < 2; ++nt) {
      f32x4 ps = {0.f, 0.f, 0.f, 0.f};
#pragma unroll
      for (int mt = 0; mt < 4; ++mt) {
        const int i = mt * 16 + l16;
        bf16x4 outv;
#pragma unroll
        for (int r = 0; r < 4; ++r) {
          float vv = fmaxf(acc[jc][mt][nt][r], 0.f);
          ps[r] += vv;
          outv[r] = (bf16_t)vv;
        }
        *(bf16x4*)&Os[jc][i][c0[nt]] = outv;
      }
#pragma unroll
      for (int m = 1; m <= 8; m <<= 1) {
#pragma unroll
        for (int r = 0; r < 4; ++r) ps[r] += __shfl_xor(ps[r], m);
      }
      if (l16 == 0) *(f32x4*)&in_s[jc][c0[nt]] = ps;  // pve -> LDS
    }
  }
  if (tid < 16) *(f32x4*)&in_s[tid >> 3][128 + (tid & 7) * 4] = v0reg;
  __syncthreads();
  {  // contiguous 32KB copy-out to transposed layout
    bf16_t* ebase = &e_ws[((size_t)(b * 64 + j0) * 64) * 128];
#pragma unroll
    for (int t = 0; t < 8; ++t) {
      int idx = tid + t * 256;
      *(int4*)&ebase[idx * 8] =
          *(const int4*)&Os[idx >> 10][(idx >> 4) & 63][(idx & 15) * 8];
    }
  }
  const int khalf = w >> 1, cbase = (w & 1) << 6;
  const int c = tid & 127, h = tid >> 7;
  {  // tail1 partials: vr = relu(concat(pve,v0)@vW + vb); K=160, k-split 80/80
    float p0 = 0.f, p1 = 0.f;
    const float* Wp = &vW[(khalf * 80) * 128 + cbase + lane];
    const float* xs0 = &in_s[0][khalf * 80];
    const float* xs1 = &in_s[1][khalf * 80];
#pragma unroll 4
    for (int kk = 0; kk < 80; kk += 4) {
      float wa = Wp[(kk + 0) * 128], wb = Wp[(kk + 1) * 128];
      float wc = Wp[(kk + 2) * 128], wd = Wp[(kk + 3) * 128];
      float4 x0 = *(const float4*)&xs0[kk];
      float4 x1 = *(const float4*)&xs1[kk];
      p0 += x0.x * wa + x0.y * wb + x0.z * wc + x0.w * wd;
      p1 += x1.x * wa + x1.y * wb + x1.z * wc + x1.w * wd;
    }
    red[khalf][0][cbase + lane] = p0;
    red[khalf][1][cbase + lane] = p1;
  }
  bar_lgkm();
  {  // tail1 reduce
    float vacc = vb[c] + red[0][h][c] + red[1][h][c];
    float vr = fmaxf(vacc, 0.f);
    v[(b * 64 + j0 + h) * 128 + c] = vr;
    vr_s[h][c] = vr;
  }
  bar_lgkm();
  {  // tail2 partials: evB = vr @ evW0 + evb; K=128, k-split 64/64
    float p0 = 0.f, p1 = 0.f;
    const float* Wp = &evW0[(khalf << 6) * 128 + cbase + lane];
    const float* xs0 = &vr_s[0][khalf << 6];
    const float* xs1 = &vr_s[1][khalf << 6];
#pragma unroll 4
    for (int kk = 0; kk < 64; kk += 4) {
      float wa = Wp[(kk + 0) * 128], wb = Wp[(kk + 1) * 128];
      float wc = Wp[(kk + 2) * 128], wd = Wp[(kk + 3) * 128];
      float4 x0 = *(const float4*)&xs0[kk];
      float4 x1 = *(const float4*)&xs1[kk];
      p0 += x0.x * wa + x0.y * wb + x0.z * wc + x0.w * wd;
      p1 += x1.x * wa + x1.y * wb + x1.z * wc + x1.w * wd;
    }
    red[khalf][0][cbase + lane] = p0;
    red[khalf][1][cbase + lane] = p1;
  }
  bar_lgkm();
  evB[(b * 64 + j0 + h) * 128 + c] = evb[c] + red[0][h][c] + red[1][h][c];
}

// ------------- inner edge pass + fused v-update & BN stats ------------------------
// e_t[b][j][i][c]: block (b,j0) owns a contiguous 32KB region AND v rows j0..j0+1.
// e += relu(e@W + eb + ev_i + ev_j); pve (pre-residual col sums) stays in LDS;
// v = relu(concat(pve,v)@vW + vb) + v (2-way k-split tail); BN stats atomics.
// LAST: e write-back replaced by edot[b][j][i] = dot(e_new[b,i,j,:], eW3).
template <bool LAST>
__global__ __launch_bounds__(256) void k_edge_inner(bf16_t* __restrict__ e_ws,
    const bf16_t* __restrict__ Wt, const float* __restrict__ eb,
    const float* __restrict__ ev, const float* __restrict__ eW3,
    float* __restrict__ edt, float* __restrict__ v,
    const float* __restrict__ vW, const float* __restrict__ vb,
    float* __restrict__ stats) {
  __shared__ bf16_t As[2][64][136];   // [jc][i][c], +8 pad
  __shared__ float W3s[128];
  __shared__ float in_s[2][256];      // [jc][ pve(128) | vrow(128) ]
  __shared__ float red[2][2][128];    // [khalf][h][c]
  __shared__ float part[4][2];
  const int b = blockIdx.x >> 5, j0 = (blockIdx.x & 31) * 2;
  const int tid = threadIdx.x;
  const int lane = tid & 63, w = tid >> 6;
  const int quad = lane >> 4, l16 = lane & 15;
  bf16_t* ebase = &e_ws[((size_t)(b * 64 + j0) * 64) * 128];
  // stage 2 e columns: one contiguous 32KB stream
  int4 stg[8];
#pragma unroll
  for (int t = 0; t < 8; ++t) {
    int idx = tid + t * 256;
    stg[t] = *(const int4*)&ebase[idx * 8];
  }
  f32x4 vreg;
  if (tid < 64)
    vreg = *(const f32x4*)&v[(b * 64 + j0 + (tid >> 5)) * 128 + (tid & 31) * 4];
  if (LAST) {
    if (tid < 128) W3s[tid] = eW3[tid];
  }
  // W A-frags in registers (L2-hot): A[m=c][k]
  bf16x8 wf[2][4];
#pragma unroll
  for (int nt = 0; nt < 2; ++nt)
#pragma unroll
    for (int ks = 0; ks < 4; ++ks)
      wf[nt][ks] = *(const bf16x8*)&Wt[(w * 32 + nt * 16 + l16) * 128 + ks * 32 + quad * 8];
  const int c0[2] = {w * 32 + quad * 4, w * 32 + 16 + quad * 4};
  // acc init = eb + ev_j + ev_i (pre-barrier loads)
  f32x4 acc[2][4][2];
  {
    f32x4 ebv[2], evj[2][2], evi[4][2];
#pragma unroll
    for (int nt = 0; nt < 2; ++nt) {
      ebv[nt] = *(const f32x4*)&eb[c0[nt]];
#pragma unroll
      for (int jc = 0; jc < 2; ++jc)
        evj[jc][nt] = *(const f32x4*)&ev[(b * 64 + j0 + jc) * 128 + c0[nt]];
#pragma unroll
      for (int mt = 0; mt < 4; ++mt)
        evi[mt][nt] = *(const f32x4*)&ev[(b * 64 + mt * 16 + l16) * 128 + c0[nt]];
    }
#pragma unroll
    for (int jc = 0; jc < 2; ++jc)
#pragma unroll
      for (int mt = 0; mt < 4; ++mt)
#pragma unroll
        for (int nt = 0; nt < 2; ++nt)
          acc[jc][mt][nt] = ebv[nt] + evj[jc][nt] + evi[mt][nt];
  }
#pragma unroll
  for (int t = 0; t < 8; ++t) {
    int idx = tid + t * 256;
    *(int4*)&As[idx >> 10][(idx >> 4) & 63][(idx & 15) * 8] = stg[t];
  }
  bar_lgkm();
  // MFMA: D[c][i] = sum_k Wt[c][k] * e[i][k]  (64 MFMA per block)
#pragma unroll
  for (int ks = 0; ks < 4; ++ks) {
    bf16x8 ef[2][4];
#pragma unroll
    for (int jc = 0; jc < 2; ++jc)
#pragma unroll
      for (int mt = 0; mt < 4; ++mt)
        ef[jc][mt] = *(const bf16x8*)&As[jc][mt * 16 + l16][ks * 32 + quad * 8];
#pragma unroll
    for (int jc = 0; jc < 2; ++jc)
#pragma unroll
      for (int mt = 0; mt < 4; ++mt)
#pragma unroll
        for (int nt = 0; nt < 2; ++nt)
          acc[jc][mt][nt] = __builtin_amdgcn_mfma_f32_16x16x32_bf16(wf[nt][ks], ef[jc][mt], acc[jc][mt][nt], 0, 0, 0);
  }
  bar_lgkm();  // all MFMA frag reads of As done (LDS-only dep)
  // epilogue: relu, pve->LDS, residual from LDS, packed writes to own cells
#pragma unroll
  for (int jc = 0; jc < 2; ++jc) {
#pragma unroll
    for (int nt = 0; nt < 2; ++nt) {
      f32x4 ps = {0.f, 0.f, 0.f, 0.f};
#pragma unroll
      for (int mt = 0; mt < 4; ++mt) {
        const int i = mt * 16 + l16;
        bf16x4 eo = *(const bf16x4*)&As[jc][i][c0[nt]];
        bf16x4 outv;
#pragma unroll
        for (int r = 0; r < 4; ++r) {
          float vv = fmaxf(acc[jc][mt][nt][r], 0.f);
          ps[r] += vv;                            // pve is pre-residual
          outv[r] = (bf16_t)(vv + (float)eo[r]);  // residual
        }
        *(bf16x4*)&As[jc][i][c0[nt]] = outv;
      }
#pragma unroll
      for (int m = 1; m <= 8; m <<= 1) {  // reduce over i (l16 lanes)
#pragma unroll
        for (int r = 0; r < 4; ++r) ps[r] += __shfl_xor(ps[r], m);
      }
      if (l16 == 0) *(f32x4*)&in_s[jc][c0[nt]] = ps;  // pve -> LDS
    }
  }
  if (tid < 64) *(f32x4*)&in_s[tid >> 5][128 + (tid & 31) * 4] = vreg;
  bar_lgkm();  // As + in_s fully updated (LDS-only dep)
  // tail partials first (issues coalesced L2 weight loads early), k-split:
  // waves 0,1 -> k in [0,128); waves 2,3 -> k in [128,256). lane = c offset.
  const int khalf = w >> 1, cbase = (w & 1) << 6;
  float p0 = 0.f, p1 = 0.f;
  {
    const float* Wp = &vW[(khalf << 7) * 128 + cbase + lane];
    const float* xs0 = &in_s[0][khalf << 7];
    const float* xs1 = &in_s[1][khalf << 7];
#pragma unroll 4
    for (int kk = 0; kk < 128; kk += 4) {
      float wa = Wp[(kk + 0) * 128], wb = Wp[(kk + 1) * 128];
      float wc = Wp[(kk + 2) * 128], wd = Wp[(kk + 3) * 128];
      float4 x0 = *(const float4*)&xs0[kk];
      float4 x1 = *(const float4*)&xs1[kk];
      p0 += x0.x * wa + x0.y * wb + x0.z * wc + x0.w * wd;
      p1 += x1.x * wa + x1.y * wb + x1.z * wc + x1.w * wd;
    }
  }
  if (!LAST) {
    // contiguous 32KB write-back
#pragma unroll
    for (int t = 0; t < 8; ++t) {
      int idx = tid + t * 256;
      *(int4*)&ebase[idx * 8] =
          *(const int4*)&As[idx >> 10][(idx >> 4) & 63][(idx & 15) * 8];
    }
  } else {
    // edot[b][j][i] = dot(e_new[b,i,j,:], W3)
    const int i = tid >> 2, q = tid & 3;
#pragma unroll
    for (int jc = 0; jc < 2; ++jc) {
      float d = 0.f;
#pragma unroll
      for (int t = 0; t < 4; ++t) {
        bf16x8 x = *(const bf16x8*)&As[jc][i][q * 32 + t * 8];
#pragma unroll
        for (int u = 0; u < 8; ++u) d += (float)x[u] * W3s[q * 32 + t * 8 + u];
      }
      d += __shfl_xor(d, 1);
      d += __shfl_xor(d, 2);
      if (q == 0) edt[(b * 64 + j0 + jc) * 64 + i] = d;
    }
  }
  red[khalf][0][cbase + lane] = p0;
  red[khalf][1][cbase + lane] = p1;
  bar_lgkm();
  // tail reduce: v = relu(vacc) + v_old; BN stats
  const int c = tid & 127, h = tid >> 7;
  float vacc = vb[c] + red[0][h][c] + red[1][h][c];
  float vnew = fmaxf(vacc, 0.f) + in_s[h][128 + c];  // relu + residual
  v[(b * 64 + j0 + h) * 128 + c] = vnew;
  // BN stats: butterfly over each 64-lane wave (one wave = 64 c's of one j)
  float s = vnew, s2 = vnew * vnew;
#pragma unroll
  for (int m = 1; m <= 32; m <<= 1) {
    s += __shfl_xor(s, m);
    s2 += __shfl_xor(s2, m);
  }
  if (lane == 0) { part[w][0] = s; part[w][1] = s2; }
  bar_lgkm();
  if (tid < 2) {
    int n = j0 + tid;
    atomicAdd(&stats[n], part[tid * 2][0] + part[tid * 2 + 1][0]);
    atomicAdd(&stats[64 + n], part[tid * 2][1] + part[tid * 2 + 1][1]);
  }
}

// ------------- g3 final: per-b block. BN(v), ev3, out_e = edot+eb3+ev3_i+ev3_j,
// pve3 in LDS, out_v. One kernel, 64 blocks. -------------
__global__ __launch_bounds__(256) void k_g3(const float* __restrict__ vv,
    const float* __restrict__ stats3, const float* __restrict__ g,
    const float* __restrict__ bt, const float* __restrict__ evW3,
    const float* __restrict__ evb3, const float* __restrict__ eb3,
    const float* __restrict__ edt, const float* __restrict__ vW3,
    const float* __restrict__ vb3, float* __restrict__ out_v,
    float* __restrict__ out_e) {
  __shared__ float vbn[64][132];   // +4 pad
  __shared__ float edts[64][68];   // edt[b][j][i], +4 pad
  __shared__ float scs[64], shs[64];
  __shared__ float W3e[128];
  __shared__ float vWs[132];
  __shared__ float ev3s[64];
  __shared__ float pj[4][64];
  const int b = blockIdx.x, tid = threadIdx.x;
  if (tid < 64) {
    float mu = stats3[tid] * (1.f / 8192.f);
    float var = stats3[64 + tid] * (1.f / 8192.f) - mu * mu;
    float sc = rsqrtf(var + 128.f) * g[tid];
    scs[tid] = sc;
    shs[tid] = bt[tid] - mu * sc;
  }
  if (tid < 128) W3e[tid] = evW3[tid];
  if (tid < 129) vWs[tid] = vW3[tid];
  __syncthreads();
#pragma unroll
  for (int t = 0; t < 8; ++t) {  // stage BN(v[b])
    int idx = t * 1024 + tid * 4;
    int row = idx >> 7, cc = idx & 127;
    f32x4 x = *(const f32x4*)&vv[(b * 64 + row) * 128 + cc];
    *(f32x4*)&vbn[row][cc] = x * scs[row] + shs[row];
  }
#pragma unroll
  for (int t = 0; t < 4; ++t) {  // stage edot[b]
    int idx = t * 1024 + tid * 4;
    int j = idx >> 6, i = idx & 63;
    *(f32x4*)&edts[j][i] = *(const f32x4*)&edt[(b * 64 + j) * 64 + i];
  }
  __syncthreads();
  {  // ev3s[i] = dot(vbn[i], W3e) + evb3
    int i = tid >> 2, q = tid & 3;
    float d = 0.f;
#pragma unroll
    for (int u = 0; u < 32; ++u) d += vbn[i][q * 32 + u] * W3e[q * 32 + u];
    d += __shfl_xor(d, 1);
    d += __shfl_xor(d, 2);
    if (q == 0) ev3s[i] = d + evb3[0];
  }
  __syncthreads();
  {  // out_e + per-j partial sums
    int q = tid >> 6, j = tid & 63;
    float s = 0.f;
    const float e3 = eb3[0];
    const float evj = ev3s[j];
#pragma unroll
    for (int r = 0; r < 16; ++r) {
      int i = q * 16 + r;
      float val = edts[j][i] + e3 + ev3s[i] + evj;
      out_e[(b * 64 + i) * 64 + j] = val;
      s += val;
    }
    pj[q][j] = s;
  }
  __syncthreads();
  {  // out_v[b,n] = pve3*vW[0] + dot(vbn[n], vW[1:129]) + vb
    int n = tid >> 2, q = tid & 3;
    float d = 0.f;
#pragma unroll
    for (int u = 0; u < 32; ++u) d += vbn[n][q * 32 + u] * vWs[1 + q * 32 + u];
    d += __shfl_xor(d, 1);
    d += __shfl_xor(d, 2);
    if (q == 0) {
      float p3 = pj[0][n] + pj[1][n] + pj[2][n] + pj[3][n];
      out_v[b * 64 + n] = d + p3 * vWs[0] + vb3[0];
    }
  }
}

extern "C" void kernel_launch(void* const* d_in, const int* in_sizes, int n_in,
                              void* d_out, int out_size, void* d_ws, size_t ws_size,
                              hipStream_t stream) {
  const float* in_v    = (const float*)d_in[0];
  const float* in_e    = (const float*)d_in[1];
  const float* bn_in_g = (const float*)d_in[2];
  const float* bn_in_b = (const float*)d_in[3];
  const float* g1_evW  = (const float*)d_in[4];
  const float* g1_evb  = (const float*)d_in[5];
  const float* g1_eW   = (const float*)d_in[6];
  const float* g1_eb   = (const float*)d_in[7];
  const float* g1_vW   = (const float*)d_in[8];
  const float* g1_vb   = (const float*)d_in[9];
  const float* inn_evW = (const float*)d_in[10];
  const float* inn_evb = (const float*)d_in[11];
  const float* inn_eW  = (const float*)d_in[12];
  const float* inn_eb  = (const float*)d_in[13];
  const float* inn_vW  = (const float*)d_in[14];
  const float* inn_vb  = (const float*)d_in[15];
  const float* bn_g    = (const float*)d_in[16];
  const float* bn_b    = (const float*)d_in[17];
  const float* g3_evW  = (const float*)d_in[18];
  const float* g3_evb  = (const float*)d_in[19];
  const float* g3_eW   = (const float*)d_in[20];
  const float* g3_eb   = (const float*)d_in[21];
  const float* g3_vW   = (const float*)d_in[22];
  const float* g3_vb   = (const float*)d_in[23];

  char* ws = (char*)d_ws;
  bf16_t* e_ws = (bf16_t*)(ws);                       // 64MB : e_t[b][j][i][c] bf16
  float* v     = (float*)(ws + 67108864);             // 2MB
  float* evA   = (float*)(ws + 69206016);             // 2MB : g1's ev
  float* evB   = (float*)(ws + 71303168);             // 2MB : inner-layer ev
  float* v0    = (float*)(ws + 73400320);             // 512KB
  bf16_t* Wt   = (bf16_t*)(ws + 73924608);            // 128KB (MFMA bf16)
  float* edt   = (float*)(ws + 74055680);             // 1MB : edot[b][j][i]
  float* stats = (float*)(ws + 75104256);             // 2KB (4 layers x 128 f32)

  float* out_v = (float*)d_out;          // [B,N,1] = 4096
  float* out_e = (float*)d_out + 4096;   // [B,N,N,1] = 262144

  k_prep<<<265, 256, 0, stream>>>(in_v, bn_in_g, bn_in_b, inn_eW, v0, Wt, stats);

  // ---- g1 (edge + fused v + fused layer-0 ev) ----
  k_ev<32><<<512, 256, 0, stream>>>(v0, g1_evW, g1_evb, evA);
  k_edge_g1<<<2048, 256, 0, stream>>>(in_e, g1_eW, g1_eb, evA, e_ws,
                                      v0, g1_vW, g1_vb, inn_evW, inn_evb, v, evB);

  // ---- inner layers: [evbn] -> edge(+v+stats) ----
  for (int l = 0; l < 4; ++l) {
    if (l > 0)
      k_evbn<<<512, 256, 0, stream>>>(v, stats + (l - 1) * 128, bn_g + (l - 1) * 64,
                                      bn_b + (l - 1) * 64, inn_evW + l * 16384,
                                      inn_evb + l * 128, evB);
    if (l < 3)
      k_edge_inner<false><<<2048, 256, 0, stream>>>(e_ws, Wt + l * 16384,
          inn_eb + l * 128, evB, g3_eW, edt, v,
          inn_vW + l * 32768, inn_vb + l * 128, stats + l * 128);
    else
      k_edge_inner<true><<<2048, 256, 0, stream>>>(e_ws, Wt + l * 16384,
          inn_eb + l * 128, evB, g3_eW, edt, v,
          inn_vW + l * 32768, inn_vb + l * 128, stats + l * 128);
  }

  // ---- g3 final (BN of layer 3 on the fly; pve3 in-block) ----
  k_g3<<<64, 256, 0, stream>>>(v, stats + 384, bn_g + 192, bn_b + 192,
                               g3_evW, g3_evb, g3_eb, edt, g3_vW, g3_vb,
                               out_v, out_e);
}

// Round 7
// 369.076 us; speedup vs baseline: 1.5617x; 1.0188x over previous
//
#include <hip/hip_runtime.h>
#include <hip/hip_bf16.h>

// GraphVertEdgeNet on MI355X. B=64, N=64, VF=32, EF=16, DV=DE=128, LN=4.
// e stored bf16 in ws (64MB) in TRANSPOSED layout e_t[b][j][i][c].
// Round-7: round-6 fused structure + bf16-PACKED tail/evbn weights.
// prep packs W[k][c] pairs into uint4 streams: Wp[k8][c] holds k=8*k8..8*k8+7
// for column c (k-contiguous per lane, lane axis stays on c -> 1KB/inst fully
// coalesced). Per-lane tail loads 128 -> 16, weight bytes per block halved.
// Inputs + accumulation stay fp32; only weights rounded to bf16 (~0.4% rel,
// weights ~N(0,1e-4)). MFMA path, k_ev, k_g3 unchanged.

typedef __bf16 bf16_t;
typedef __bf16 bf16x8 __attribute__((ext_vector_type(8)));
typedef __bf16 bf16x4 __attribute__((ext_vector_type(4)));
typedef float f32x4 __attribute__((ext_vector_type(4)));

// Barrier that does NOT drain vmcnt: safe when cross-wave deps are LDS-only.
__device__ __forceinline__ void bar_lgkm() {
  asm volatile("s_waitcnt lgkmcnt(0)\n\ts_barrier" ::: "memory");
}

__device__ __forceinline__ unsigned pack2(float a, float b) {
  bf16_t ba = (bf16_t)a, bb = (bf16_t)b;
  unsigned short ua, ub;
  __builtin_memcpy(&ua, &ba, 2);
  __builtin_memcpy(&ub, &bb, 2);
  return (unsigned)ua | ((unsigned)ub << 16);
}
__device__ __forceinline__ float blo(unsigned u) {
  unsigned v = u << 16; float f; __builtin_memcpy(&f, &v, 4); return f;
}
__device__ __forceinline__ float bhi(unsigned u) {
  unsigned v = u & 0xffff0000u; float f; __builtin_memcpy(&f, &v, 4); return f;
}

// ---------------- prep: input BN (v0), Wt transpose, packed weights, zero stats -----------
__global__ __launch_bounds__(256) void k_prep(const float* __restrict__ vin,
    const float* __restrict__ g, const float* __restrict__ bt,
    const float* __restrict__ eW, const float* __restrict__ inn_vW,
    const float* __restrict__ g1_vW, const float* __restrict__ inn_evW,
    float* __restrict__ v0, bf16_t* __restrict__ Wt, float* __restrict__ stats,
    unsigned* __restrict__ vWp, unsigned* __restrict__ g1_vWp,
    unsigned* __restrict__ evWp) {
  const int blk = blockIdx.x, tid = threadIdx.x;
  if (blk < 8) {  // BatchNorm1d(N*VF) over batch, ch = 0..2047
    int ch = blk * 256 + tid;
    float s = 0.f, s2 = 0.f;
    for (int b = 0; b < 64; ++b) { float x = vin[b * 2048 + ch]; s += x; s2 += x * x; }
    float mu = s * (1.f / 64.f);
    float var = s2 * (1.f / 64.f) - mu * mu;  // biased var
    float sc = rsqrtf(var + 1e-5f) * g[ch];
    float bb = bt[ch];
    for (int b = 0; b < 64; ++b) {
      float x = vin[b * 2048 + ch];
      v0[b * 2048 + ch] = (x - mu) * sc + bb;
    }
  } else if (blk < 264) {  // Wt[l][n][k] = eW[l][k][n] as bf16 (MFMA operand)
    int idx = (blk - 8) * 256 + tid;  // 65536
    int l = idx >> 14, r = idx & 16383, n = r >> 7, k = r & 127;
    Wt[idx] = (bf16_t)eW[(l << 14) + (k << 7) + n];
  } else if (blk == 264) {  // zero stats (512 f32)
    for (int i = tid; i < 512; i += 256) stats[i] = 0.f;
  } else if (blk < 521) {  // vWp[l][k8][c][j]: inn_vW [4][256][128] packed
    int idx = (blk - 265) * 256 + tid;  // 65536 u32
    int l = idx >> 14, r = idx & 16383;
    int k8 = r >> 9, c = (r >> 2) & 127, j = r & 3;
    int ka = k8 * 8 + j * 2;
    vWp[idx] = pack2(inn_vW[(l << 15) + ka * 128 + c],
                     inn_vW[(l << 15) + (ka + 1) * 128 + c]);
  } else if (blk < 561) {  // g1_vWp[k8][c][j]: g1_vW [160][128] packed
    int idx = (blk - 521) * 256 + tid;  // 10240 u32
    int k8 = idx >> 9, c = (idx >> 2) & 127, j = idx & 3;
    int ka = k8 * 8 + j * 2;
    g1_vWp[idx] = pack2(g1_vW[ka * 128 + c], g1_vW[(ka + 1) * 128 + c]);
  } else {  // evWp[l][k8][c][j]: inn_evW [4][128][128] packed  (blk < 689)
    int idx = (blk - 561) * 256 + tid;  // 32768 u32
    int l = idx >> 13, r = idx & 8191;
    int k8 = r >> 9, c = (r >> 2) & 127, j = r & 3;
    int ka = k8 * 8 + j * 2;
    evWp[idx] = pack2(inn_evW[(l << 14) + ka * 128 + c],
                      inn_evW[(l << 14) + (ka + 1) * 128 + c]);
  }
}

// ------------- ev = v_in @ W + bias : [4096,K]@[K,128]. 256 thr, 8 rows/blk -------------
template <int K>
__global__ __launch_bounds__(256) void k_ev(const float* __restrict__ v_in,
    const float* __restrict__ W, const float* __restrict__ bias,
    float* __restrict__ out) {
  __shared__ float rows_s[8][K];
  const int r0 = blockIdx.x * 8;
  const int tid = threadIdx.x;
  const int c = tid & 127, h = tid >> 7;  // h: rows h*4 .. h*4+3
  for (int idx = tid; idx < 8 * K; idx += 256) {
    int rr = idx / K, kk = idx % K;
    rows_s[rr][kk] = v_in[(r0 + rr) * K + kk];
  }
  __syncthreads();
  float acc[4];
  const float bv = bias[c];
#pragma unroll
  for (int r = 0; r < 4; ++r) acc[r] = bv;
  for (int k4 = 0; k4 < K; k4 += 4) {
    float w0 = W[(k4 + 0) * 128 + c], w1 = W[(k4 + 1) * 128 + c];
    float w2 = W[(k4 + 2) * 128 + c], w3 = W[(k4 + 3) * 128 + c];
#pragma unroll
    for (int r = 0; r < 4; ++r) {
      float4 x = *(const float4*)&rows_s[h * 4 + r][k4];
      acc[r] += x.x * w0 + x.y * w1 + x.z * w2 + x.w * w3;
    }
  }
#pragma unroll
  for (int r = 0; r < 4; ++r) out[(r0 + h * 4 + r) * 128 + c] = acc[r];
}

// ------------- fused BN(prev) + ev matmul (packed bf16 weights). 8 rows/blk -------------
__global__ __launch_bounds__(256) void k_evbn(float* __restrict__ v,
    const float* __restrict__ stats, const float* __restrict__ g,
    const float* __restrict__ bt, const uint4* __restrict__ Wp,
    const float* __restrict__ bias, float* __restrict__ out) {
  __shared__ float rows_s[8][128];
  const int r0 = blockIdx.x * 8;
  const int tid = threadIdx.x;
  const int c = tid & 127, h = tid >> 7;
#pragma unroll
  for (int u = 0; u < 4; ++u) {
    int idx = u * 256 + tid;
    int rr = idx >> 7, k = idx & 127;
    int n = (r0 + rr) & 63;
    float mu = stats[n] * (1.f / 8192.f);
    float var = stats[64 + n] * (1.f / 8192.f) - mu * mu;
    float sc = rsqrtf(var + 128.f) * g[n];
    float x = (v[(r0 + rr) * 128 + k] - mu) * sc + bt[n];
    rows_s[rr][k] = x;
    v[(r0 + rr) * 128 + k] = x;  // normalized v for residual/concat
  }
  __syncthreads();
  float acc[4];
  const float bv = bias[c];
#pragma unroll
  for (int r = 0; r < 4; ++r) acc[r] = bv;
#pragma unroll 4
  for (int k8 = 0; k8 < 16; ++k8) {
    uint4 wv = Wp[k8 * 128 + c];
    float we0 = blo(wv.x), wo0 = bhi(wv.x);
    float we1 = blo(wv.y), wo1 = bhi(wv.y);
    float we2 = blo(wv.z), wo2 = bhi(wv.z);
    float we3 = blo(wv.w), wo3 = bhi(wv.w);
#pragma unroll
    for (int r = 0; r < 4; ++r) {
      float4 xa = *(const float4*)&rows_s[h * 4 + r][k8 * 8];
      float4 xb = *(const float4*)&rows_s[h * 4 + r][k8 * 8 + 4];
      acc[r] += xa.x * we0 + xa.y * wo0 + xa.z * we1 + xa.w * wo1
              + xb.x * we2 + xb.y * wo2 + xb.z * we3 + xb.w * wo3;
    }
  }
#pragma unroll
  for (int r = 0; r < 4; ++r) out[(r0 + h * 4 + r) * 128 + c] = acc[r];
}

// ------------- g1 edge pass (MFMA, K 16->32 zero-pad, 2 j/block) + fused g1-v + ev0 ------
// Writes e_t[b][j][i][c] (transposed layout), v rows j0..j0+1, ev0 rows j0..j0+1.
// Tails: 2-way k-split across wave pairs, bf16-packed weights.
__global__ __launch_bounds__(256) void k_edge_g1(const float* __restrict__ e0,
    const float* __restrict__ eW, const float* __restrict__ eb,
    const float* __restrict__ evA, bf16_t* __restrict__ e_ws,
    const float* __restrict__ v0, const uint4* __restrict__ g1_vWp,
    const float* __restrict__ vb, const uint4* __restrict__ evW0p,
    const float* __restrict__ evb, float* __restrict__ v,
    float* __restrict__ evB) {
  __shared__ bf16_t A0s[2][64][40];
  __shared__ bf16_t Os[2][64][136];
  __shared__ float in_s[2][160];  // [jc][ pve(128) | v0row(32) ]
  __shared__ float vr_s[2][128];
  __shared__ float red[2][2][128];  // [khalf][h][c]
  const int b = blockIdx.x >> 5, j0 = (blockIdx.x & 31) * 2;
  const int tid = threadIdx.x;
  const int lane = tid & 63, w = tid >> 6;
  const int quad = lane >> 4, l16 = lane & 15;
  f32x4 v0reg;
  if (tid < 16)
    v0reg = *(const f32x4*)&v0[(b * 64 + j0 + (tid >> 3)) * 32 + (tid & 7) * 4];
#pragma unroll
  for (int t = 0; t < 2; ++t) {
    int idx = tid + t * 256;
    int row = idx >> 3, off = (idx & 7) * 4;
    int jc = off >> 4, k = off & 15;
    f32x4 x = *(const f32x4*)&e0[((b * 64 + row) * 64 + j0) * 16 + off];
    bf16x4 y;
#pragma unroll
    for (int r = 0; r < 4; ++r) y[r] = (bf16_t)x[r];
    *(bf16x4*)&A0s[jc][row][k] = y;
    bf16x4 z = {(bf16_t)0.f, (bf16_t)0.f, (bf16_t)0.f, (bf16_t)0.f};
    *(bf16x4*)&A0s[jc][row][16 + k] = z;
  }
  const int c0[2] = {w * 32 + quad * 4, w * 32 + 16 + quad * 4};
  bf16x8 wf[2];
#pragma unroll
  for (int nt = 0; nt < 2; ++nt) {
    const int c = w * 32 + nt * 16 + l16;
#pragma unroll
    for (int jj = 0; jj < 8; ++jj)
      wf[nt][jj] = (quad < 2) ? (bf16_t)eW[(quad * 8 + jj) * 128 + c] : (bf16_t)0.f;
  }
  f32x4 acc[2][4][2];
  {
    f32x4 ebv[2], evj[2][2], evi[4][2];
#pragma unroll
    for (int nt = 0; nt < 2; ++nt) {
      ebv[nt] = *(const f32x4*)&eb[c0[nt]];
#pragma unroll
      for (int jc = 0; jc < 2; ++jc)
        evj[jc][nt] = *(const f32x4*)&evA[(b * 64 + j0 + jc) * 128 + c0[nt]];
#pragma unroll
      for (int mt = 0; mt < 4; ++mt)
        evi[mt][nt] = *(const f32x4*)&evA[(b * 64 + mt * 16 + l16) * 128 + c0[nt]];
    }
#pragma unroll
    for (int jc = 0; jc < 2; ++jc)
#pragma unroll
      for (int mt = 0; mt < 4; ++mt)
#pragma unroll
        for (int nt = 0; nt < 2; ++nt)
          acc[jc][mt][nt] = ebv[nt] + evj[jc][nt] + evi[mt][nt];
  }
  __syncthreads();
#pragma unroll
  for (int jc = 0; jc < 2; ++jc) {
#pragma unroll
    for (int mt = 0; mt < 4; ++mt) {
      bf16x8 ef = *(const bf16x8*)&A0s[jc][mt * 16 + l16][quad * 8];
#pragma unroll
      for (int nt = 0; nt < 2; ++nt)
        acc[jc][mt][nt] = __builtin_amdgcn_mfma_f32_16x16x32_bf16(wf[nt], ef, acc[jc][mt][nt], 0, 0, 0);
    }
  }
#pragma unroll
  for (int jc = 0; jc < 2; ++jc) {
#pragma unroll
    for (int nt = 0; nt < 2; ++nt) {
      f32x4 ps = {0.f, 0.f, 0.f, 0.f};
#pragma unroll
      for (int mt = 0; mt < 4; ++mt) {
        const int i = mt * 16 + l16;
        bf16x4 outv;
#pragma unroll
        for (int r = 0; r < 4; ++r) {
          float vv = fmaxf(acc[jc][mt][nt][r], 0.f);
          ps[r] += vv;
          outv[r] = (bf16_t)vv;
        }
        *(bf16x4*)&Os[jc][i][c0[nt]] = outv;
      }
#pragma unroll
      for (int m = 1; m <= 8; m <<= 1) {
#pragma unroll
        for (int r = 0; r < 4; ++r) ps[r] += __shfl_xor(ps[r], m);
      }
      if (l16 == 0) *(f32x4*)&in_s[jc][c0[nt]] = ps;  // pve -> LDS
    }
  }
  if (tid < 16) *(f32x4*)&in_s[tid >> 3][128 + (tid & 7) * 4] = v0reg;
  __syncthreads();
  {  // contiguous 32KB copy-out to transposed layout
    bf16_t* ebase = &e_ws[((size_t)(b * 64 + j0) * 64) * 128];
#pragma unroll
    for (int t = 0; t < 8; ++t) {
      int idx = tid + t * 256;
      *(int4*)&ebase[idx * 8] =
          *(const int4*)&Os[idx >> 10][(idx >> 4) & 63][(idx & 15) * 8];
    }
  }
  const int khalf = w >> 1, cbase = (w & 1) << 6;
  const int cc = cbase + lane;
  const int c = tid & 127, h = tid >> 7;
  {  // tail1 partials: vr = relu(concat(pve,v0)@vW + vb); K=160, k-split 80/80
    float p0 = 0.f, p1 = 0.f;
    const uint4* Wp = &g1_vWp[(khalf * 10) * 128 + cc];
    const float* xs0 = &in_s[0][khalf * 80];
    const float* xs1 = &in_s[1][khalf * 80];
#pragma unroll 5
    for (int k8 = 0; k8 < 10; ++k8) {
      uint4 wv = Wp[k8 * 128];
      float we0 = blo(wv.x), wo0 = bhi(wv.x);
      float we1 = blo(wv.y), wo1 = bhi(wv.y);
      float we2 = blo(wv.z), wo2 = bhi(wv.z);
      float we3 = blo(wv.w), wo3 = bhi(wv.w);
      float4 xa0 = *(const float4*)&xs0[k8 * 8];
      float4 xb0 = *(const float4*)&xs0[k8 * 8 + 4];
      float4 xa1 = *(const float4*)&xs1[k8 * 8];
      float4 xb1 = *(const float4*)&xs1[k8 * 8 + 4];
      p0 += xa0.x * we0 + xa0.y * wo0 + xa0.z * we1 + xa0.w * wo1
          + xb0.x * we2 + xb0.y * wo2 + xb0.z * we3 + xb0.w * wo3;
      p1 += xa1.x * we0 + xa1.y * wo0 + xa1.z * we1 + xa1.w * wo1
          + xb1.x * we2 + xb1.y * wo2 + xb1.z * we3 + xb1.w * wo3;
    }
    red[khalf][0][cc] = p0;
    red[khalf][1][cc] = p1;
  }
  bar_lgkm();
  {  // tail1 reduce
    float vacc = vb[c] + red[0][h][c] + red[1][h][c];
    float vr = fmaxf(vacc, 0.f);
    v[(b * 64 + j0 + h) * 128 + c] = vr;
    vr_s[h][c] = vr;
  }
  bar_lgkm();
  {  // tail2 partials: evB = vr @ evW0 + evb; K=128, k-split 64/64
    float p0 = 0.f, p1 = 0.f;
    const uint4* Wp = &evW0p[(khalf * 8) * 128 + cc];
    const float* xs0 = &vr_s[0][khalf << 6];
    const float* xs1 = &vr_s[1][khalf << 6];
#pragma unroll 4
    for (int k8 = 0; k8 < 8; ++k8) {
      uint4 wv = Wp[k8 * 128];
      float we0 = blo(wv.x), wo0 = bhi(wv.x);
      float we1 = blo(wv.y), wo1 = bhi(wv.y);
      float we2 = blo(wv.z), wo2 = bhi(wv.z);
      float we3 = blo(wv.w), wo3 = bhi(wv.w);
      float4 xa0 = *(const float4*)&xs0[k8 * 8];
      float4 xb0 = *(const float4*)&xs0[k8 * 8 + 4];
      float4 xa1 = *(const float4*)&xs1[k8 * 8];
      float4 xb1 = *(const float4*)&xs1[k8 * 8 + 4];
      p0 += xa0.x * we0 + xa0.y * wo0 + xa0.z * we1 + xa0.w * wo1
          + xb0.x * we2 + xb0.y * wo2 + xb0.z * we3 + xb0.w * wo3;
      p1 += xa1.x * we0 + xa1.y * wo0 + xa1.z * we1 + xa1.w * wo1
          + xb1.x * we2 + xb1.y * wo2 + xb1.z * we3 + xb1.w * wo3;
    }
    red[khalf][0][cc] = p0;
    red[khalf][1][cc] = p1;
  }
  bar_lgkm();
  evB[(b * 64 + j0 + h) * 128 + c] = evb[c] + red[0][h][c] + red[1][h][c];
}

// ------------- inner edge pass + fused v-update & BN stats ------------------------
// e_t[b][j][i][c]: block (b,j0) owns a contiguous 32KB region AND v rows j0..j0+1.
// e += relu(e@W + eb + ev_i + ev_j); pve stays in LDS; v-update tail uses
// bf16-packed weights with 2-way k-split; BN stats atomics.
// LAST: e write-back replaced by edot[b][j][i] = dot(e_new[b,i,j,:], eW3).
template <bool LAST>
__global__ __launch_bounds__(256) void k_edge_inner(bf16_t* __restrict__ e_ws,
    const bf16_t* __restrict__ Wt, const float* __restrict__ eb,
    const float* __restrict__ ev, const float* __restrict__ eW3,
    float* __restrict__ edt, float* __restrict__ v,
    const uint4* __restrict__ vWp, const float* __restrict__ vb,
    float* __restrict__ stats) {
  __shared__ bf16_t As[2][64][136];   // [jc][i][c], +8 pad
  __shared__ float W3s[128];
  __shared__ float in_s[2][256];      // [jc][ pve(128) | vrow(128) ]
  __shared__ float red[2][2][128];    // [khalf][h][c]
  __shared__ float part[4][2];
  const int b = blockIdx.x >> 5, j0 = (blockIdx.x & 31) * 2;
  const int tid = threadIdx.x;
  const int lane = tid & 63, w = tid >> 6;
  const int quad = lane >> 4, l16 = lane & 15;
  bf16_t* ebase = &e_ws[((size_t)(b * 64 + j0) * 64) * 128];
  // stage 2 e columns: one contiguous 32KB stream
  int4 stg[8];
#pragma unroll
  for (int t = 0; t < 8; ++t) {
    int idx = tid + t * 256;
    stg[t] = *(const int4*)&ebase[idx * 8];
  }
  f32x4 vreg;
  if (tid < 64)
    vreg = *(const f32x4*)&v[(b * 64 + j0 + (tid >> 5)) * 128 + (tid & 31) * 4];
  if (LAST) {
    if (tid < 128) W3s[tid] = eW3[tid];
  }
  // W A-frags in registers (L2-hot): A[m=c][k]
  bf16x8 wf[2][4];
#pragma unroll
  for (int nt = 0; nt < 2; ++nt)
#pragma unroll
    for (int ks = 0; ks < 4; ++ks)
      wf[nt][ks] = *(const bf16x8*)&Wt[(w * 32 + nt * 16 + l16) * 128 + ks * 32 + quad * 8];
  const int c0[2] = {w * 32 + quad * 4, w * 32 + 16 + quad * 4};
  // acc init = eb + ev_j + ev_i (pre-barrier loads)
  f32x4 acc[2][4][2];
  {
    f32x4 ebv[2], evj[2][2], evi[4][2];
#pragma unroll
    for (int nt = 0; nt < 2; ++nt) {
      ebv[nt] = *(const f32x4*)&eb[c0[nt]];
#pragma unroll
      for (int jc = 0; jc < 2; ++jc)
        evj[jc][nt] = *(const f32x4*)&ev[(b * 64 + j0 + jc) * 128 + c0[nt]];
#pragma unroll
      for (int mt = 0; mt < 4; ++mt)
        evi[mt][nt] = *(const f32x4*)&ev[(b * 64 + mt * 16 + l16) * 128 + c0[nt]];
    }
#pragma unroll
    for (int jc = 0; jc < 2; ++jc)
#pragma unroll
      for (int mt = 0; mt < 4; ++mt)
#pragma unroll
        for (int nt = 0; nt < 2; ++nt)
          acc[jc][mt][nt] = ebv[nt] + evj[jc][nt] + evi[mt][nt];
  }
#pragma unroll
  for (int t = 0; t < 8; ++t) {
    int idx = tid + t * 256;
    *(int4*)&As[idx >> 10][(idx >> 4) & 63][(idx & 15) * 8] = stg[t];
  }
  bar_lgkm();
  // MFMA: D[c][i] = sum_k Wt[c][k] * e[i][k]  (64 MFMA per block)
#pragma unroll
  for (int ks = 0; ks < 4; ++ks) {
    bf16x8 ef[2][4];
#pragma unroll
    for (int jc = 0; jc < 2; ++jc)
#pragma unroll
      for (int mt = 0; mt < 4; ++mt)
        ef[jc][mt] = *(const bf16x8*)&As[jc][mt * 16 + l16][ks * 32 + quad * 8];
#pragma unroll
    for (int jc = 0; jc < 2; ++jc)
#pragma unroll
      for (int mt = 0; mt < 4; ++mt)
#pragma unroll
        for (int nt = 0; nt < 2; ++nt)
          acc[jc][mt][nt] = __builtin_amdgcn_mfma_f32_16x16x32_bf16(wf[nt][ks], ef[jc][mt], acc[jc][mt][nt], 0, 0, 0);
  }
  bar_lgkm();  // all MFMA frag reads of As done (LDS-only dep)
  // epilogue: relu, pve->LDS, residual from LDS, packed writes to own cells
#pragma unroll
  for (int jc = 0; jc < 2; ++jc) {
#pragma unroll
    for (int nt = 0; nt < 2; ++nt) {
      f32x4 ps = {0.f, 0.f, 0.f, 0.f};
#pragma unroll
      for (int mt = 0; mt < 4; ++mt) {
        const int i = mt * 16 + l16;
        bf16x4 eo = *(const bf16x4*)&As[jc][i][c0[nt]];
        bf16x4 outv;
#pragma unroll
        for (int r = 0; r < 4; ++r) {
          float vv = fmaxf(acc[jc][mt][nt][r], 0.f);
          ps[r] += vv;                            // pve is pre-residual
          outv[r] = (bf16_t)(vv + (float)eo[r]);  // residual
        }
        *(bf16x4*)&As[jc][i][c0[nt]] = outv;
      }
#pragma unroll
      for (int m = 1; m <= 8; m <<= 1) {  // reduce over i (l16 lanes)
#pragma unroll
        for (int r = 0; r < 4; ++r) ps[r] += __shfl_xor(ps[r], m);
      }
      if (l16 == 0) *(f32x4*)&in_s[jc][c0[nt]] = ps;  // pve -> LDS
    }
  }
  if (tid < 64) *(f32x4*)&in_s[tid >> 5][128 + (tid & 31) * 4] = vreg;
  bar_lgkm();  // As + in_s fully updated (LDS-only dep)
  // tail partials first (issues coalesced L2 weight loads early), k-split:
  // waves 0,1 -> k in [0,128); waves 2,3 -> k in [128,256). packed bf16 weights.
  const int khalf = w >> 1, cbase = (w & 1) << 6;
  const int cc = cbase + lane;
  float p0 = 0.f, p1 = 0.f;
  {
    const uint4* Wp = &vWp[(khalf * 16) * 128 + cc];
    const float* xs0 = &in_s[0][khalf << 7];
    const float* xs1 = &in_s[1][khalf << 7];
#pragma unroll 4
    for (int k8 = 0; k8 < 16; ++k8) {
      uint4 wv = Wp[k8 * 128];
      float we0 = blo(wv.x), wo0 = bhi(wv.x);
      float we1 = blo(wv.y), wo1 = bhi(wv.y);
      float we2 = blo(wv.z), wo2 = bhi(wv.z);
      float we3 = blo(wv.w), wo3 = bhi(wv.w);
      float4 xa0 = *(const float4*)&xs0[k8 * 8];
      float4 xb0 = *(const float4*)&xs0[k8 * 8 + 4];
      float4 xa1 = *(const float4*)&xs1[k8 * 8];
      float4 xb1 = *(const float4*)&xs1[k8 * 8 + 4];
      p0 += xa0.x * we0 + xa0.y * wo0 + xa0.z * we1 + xa0.w * wo1
          + xb0.x * we2 + xb0.y * wo2 + xb0.z * we3 + xb0.w * wo3;
      p1 += xa1.x * we0 + xa1.y * wo0 + xa1.z * we1 + xa1.w * wo1
          + xb1.x * we2 + xb1.y * wo2 + xb1.z * we3 + xb1.w * wo3;
    }
  }
  if (!LAST) {
    // contiguous 32KB write-back
#pragma unroll
    for (int t = 0; t < 8; ++t) {
      int idx = tid + t * 256;
      *(int4*)&ebase[idx * 8] =
          *(const int4*)&As[idx >> 10][(idx >> 4) & 63][(idx & 15) * 8];
    }
  } else {
    // edot[b][j][i] = dot(e_new[b,i,j,:], W3)
    const int i = tid >> 2, q = tid & 3;
#pragma unroll
    for (int jc = 0; jc < 2; ++jc) {
      float d = 0.f;
#pragma unroll
      for (int t = 0; t < 4; ++t) {
        bf16x8 x = *(const bf16x8*)&As[jc][i][q * 32 + t * 8];
#pragma unroll
        for (int u = 0; u < 8; ++u) d += (float)x[u] * W3s[q * 32 + t * 8 + u];
      }
      d += __shfl_xor(d, 1);
      d += __shfl_xor(d, 2);
      if (q == 0) edt[(b * 64 + j0 + jc) * 64 + i] = d;
    }
  }
  red[khalf][0][cc] = p0;
  red[khalf][1][cc] = p1;
  bar_lgkm();
  // tail reduce: v = relu(vacc) + v_old; BN stats
  const int c = tid & 127, h = tid >> 7;
  float vacc = vb[c] + red[0][h][c] + red[1][h][c];
  float vnew = fmaxf(vacc, 0.f) + in_s[h][128 + c];  // relu + residual
  v[(b * 64 + j0 + h) * 128 + c] = vnew;
  // BN stats: butterfly over each 64-lane wave (one wave = 64 c's of one j)
  float s = vnew, s2 = vnew * vnew;
#pragma unroll
  for (int m = 1; m <= 32; m <<= 1) {
    s += __shfl_xor(s, m);
    s2 += __shfl_xor(s2, m);
  }
  if (lane == 0) { part[w][0] = s; part[w][1] = s2; }
  bar_lgkm();
  if (tid < 2) {
    int n = j0 + tid;
    atomicAdd(&stats[n], part[tid * 2][0] + part[tid * 2 + 1][0]);
    atomicAdd(&stats[64 + n], part[tid * 2][1] + part[tid * 2 + 1][1]);
  }
}

// ------------- g3 final: per-b block. BN(v), ev3, out_e = edot+eb3+ev3_i+ev3_j,
// pve3 in LDS, out_v. One kernel, 64 blocks. -------------
__global__ __launch_bounds__(256) void k_g3(const float* __restrict__ vv,
    const float* __restrict__ stats3, const float* __restrict__ g,
    const float* __restrict__ bt, const float* __restrict__ evW3,
    const float* __restrict__ evb3, const float* __restrict__ eb3,
    const float* __restrict__ edt, const float* __restrict__ vW3,
    const float* __restrict__ vb3, float* __restrict__ out_v,
    float* __restrict__ out_e) {
  __shared__ float vbn[64][132];   // +4 pad
  __shared__ float edts[64][68];   // edt[b][j][i], +4 pad
  __shared__ float scs[64], shs[64];
  __shared__ float W3e[128];
  __shared__ float vWs[132];
  __shared__ float ev3s[64];
  __shared__ float pj[4][64];
  const int b = blockIdx.x, tid = threadIdx.x;
  if (tid < 64) {
    float mu = stats3[tid] * (1.f / 8192.f);
    float var = stats3[64 + tid] * (1.f / 8192.f) - mu * mu;
    float sc = rsqrtf(var + 128.f) * g[tid];
    scs[tid] = sc;
    shs[tid] = bt[tid] - mu * sc;
  }
  if (tid < 128) W3e[tid] = evW3[tid];
  if (tid < 129) vWs[tid] = vW3[tid];
  __syncthreads();
#pragma unroll
  for (int t = 0; t < 8; ++t) {  // stage BN(v[b])
    int idx = t * 1024 + tid * 4;
    int row = idx >> 7, cc = idx & 127;
    f32x4 x = *(const f32x4*)&vv[(b * 64 + row) * 128 + cc];
    *(f32x4*)&vbn[row][cc] = x * scs[row] + shs[row];
  }
#pragma unroll
  for (int t = 0; t < 4; ++t) {  // stage edot[b]
    int idx = t * 1024 + tid * 4;
    int j = idx >> 6, i = idx & 63;
    *(f32x4*)&edts[j][i] = *(const f32x4*)&edt[(b * 64 + j) * 64 + i];
  }
  __syncthreads();
  {  // ev3s[i] = dot(vbn[i], W3e) + evb3
    int i = tid >> 2, q = tid & 3;
    float d = 0.f;
#pragma unroll
    for (int u = 0; u < 32; ++u) d += vbn[i][q * 32 + u] * W3e[q * 32 + u];
    d += __shfl_xor(d, 1);
    d += __shfl_xor(d, 2);
    if (q == 0) ev3s[i] = d + evb3[0];
  }
  __syncthreads();
  {  // out_e + per-j partial sums
    int q = tid >> 6, j = tid & 63;
    float s = 0.f;
    const float e3 = eb3[0];
    const float evj = ev3s[j];
#pragma unroll
    for (int r = 0; r < 16; ++r) {
      int i = q * 16 + r;
      float val = edts[j][i] + e3 + ev3s[i] + evj;
      out_e[(b * 64 + i) * 64 + j] = val;
      s += val;
    }
    pj[q][j] = s;
  }
  __syncthreads();
  {  // out_v[b,n] = pve3*vW[0] + dot(vbn[n], vW[1:129]) + vb
    int n = tid >> 2, q = tid & 3;
    float d = 0.f;
#pragma unroll
    for (int u = 0; u < 32; ++u) d += vbn[n][q * 32 + u] * vWs[1 + q * 32 + u];
    d += __shfl_xor(d, 1);
    d += __shfl_xor(d, 2);
    if (q == 0) {
      float p3 = pj[0][n] + pj[1][n] + pj[2][n] + pj[3][n];
      out_v[b * 64 + n] = d + p3 * vWs[0] + vb3[0];
    }
  }
}

extern "C" void kernel_launch(void* const* d_in, const int* in_sizes, int n_in,
                              void* d_out, int out_size, void* d_ws, size_t ws_size,
                              hipStream_t stream) {
  const float* in_v    = (const float*)d_in[0];
  const float* in_e    = (const float*)d_in[1];
  const float* bn_in_g = (const float*)d_in[2];
  const float* bn_in_b = (const float*)d_in[3];
  const float* g1_evW  = (const float*)d_in[4];
  const float* g1_evb  = (const float*)d_in[5];
  const float* g1_eW   = (const float*)d_in[6];
  const float* g1_eb   = (const float*)d_in[7];
  const float* g1_vW   = (const float*)d_in[8];
  const float* g1_vb   = (const float*)d_in[9];
  const float* inn_evW = (const float*)d_in[10];
  const float* inn_evb = (const float*)d_in[11];
  const float* inn_eW  = (const float*)d_in[12];
  const float* inn_eb  = (const float*)d_in[13];
  const float* inn_vW  = (const float*)d_in[14];
  const float* inn_vb  = (const float*)d_in[15];
  const float* bn_g    = (const float*)d_in[16];
  const float* bn_b    = (const float*)d_in[17];
  const float* g3_evW  = (const float*)d_in[18];
  const float* g3_evb  = (const float*)d_in[19];
  const float* g3_eW   = (const float*)d_in[20];
  const float* g3_eb   = (const float*)d_in[21];
  const float* g3_vW   = (const float*)d_in[22];
  const float* g3_vb   = (const float*)d_in[23];

  char* ws = (char*)d_ws;
  bf16_t* e_ws = (bf16_t*)(ws);                       // 64MB : e_t[b][j][i][c] bf16
  float* v        = (float*)(ws + 67108864);          // 2MB
  float* evA      = (float*)(ws + 69206016);          // 2MB : g1's ev
  float* evB      = (float*)(ws + 71303168);          // 2MB : inner-layer ev
  float* v0       = (float*)(ws + 73400320);          // 512KB
  bf16_t* Wt      = (bf16_t*)(ws + 73924608);         // 128KB (MFMA bf16)
  float* edt      = (float*)(ws + 74055680);          // 1MB : edot[b][j][i]
  float* stats    = (float*)(ws + 75104256);          // 2KB
  unsigned* vWp   = (unsigned*)(ws + 75106304);       // 256KB [4][32][128] uint4
  unsigned* g1_vWp= (unsigned*)(ws + 75368448);       // 40KB  [20][128] uint4
  unsigned* evWp  = (unsigned*)(ws + 75409408);       // 128KB [4][16][128] uint4

  float* out_v = (float*)d_out;          // [B,N,1] = 4096
  float* out_e = (float*)d_out + 4096;   // [B,N,N,1] = 262144

  k_prep<<<689, 256, 0, stream>>>(in_v, bn_in_g, bn_in_b, inn_eW, inn_vW, g1_vW,
                                  inn_evW, v0, Wt, stats, vWp, g1_vWp, evWp);

  // ---- g1 (edge + fused v + fused layer-0 ev) ----
  k_ev<32><<<512, 256, 0, stream>>>(v0, g1_evW, g1_evb, evA);
  k_edge_g1<<<2048, 256, 0, stream>>>(in_e, g1_eW, g1_eb, evA, e_ws,
                                      v0, (const uint4*)g1_vWp, g1_vb,
                                      (const uint4*)evWp, inn_evb, v, evB);

  // ---- inner layers: [evbn] -> edge(+v+stats) ----
  for (int l = 0; l < 4; ++l) {
    if (l > 0)
      k_evbn<<<512, 256, 0, stream>>>(v, stats + (l - 1) * 128, bn_g + (l - 1) * 64,
                                      bn_b + (l - 1) * 64,
                                      (const uint4*)evWp + l * 2048,
                                      inn_evb + l * 128, evB);
    if (l < 3)
      k_edge_inner<false><<<2048, 256, 0, stream>>>(e_ws, Wt + l * 16384,
          inn_eb + l * 128, evB, g3_eW, edt, v,
          (const uint4*)vWp + l * 4096, inn_vb + l * 128, stats + l * 128);
    else
      k_edge_inner<true><<<2048, 256, 0, stream>>>(e_ws, Wt + l * 16384,
          inn_eb + l * 128, evB, g3_eW, edt, v,
          (const uint4*)vWp + l * 4096, inn_vb + l * 128, stats + l * 128);
  }

  // ---- g3 final (BN of layer 3 on the fly; pve3 in-block) ----
  k_g3<<<64, 256, 0, stream>>>(v, stats + 384, bn_g + 192, bn_b + 192,
                               g3_evW, g3_evb, g3_eb, edt, g3_vW, g3_vb,
                               out_v, out_e);
}

// Round 8
// 367.513 us; speedup vs baseline: 1.5683x; 1.0043x over previous
//
#include <hip/hip_runtime.h>
#include <hip/hip_bf16.h>

// GraphVertEdgeNet on MI355X. B=64, N=64, VF=32, EF=16, DV=DE=128, LN=4.
// e stored bf16 in ws (64MB) in TRANSPOSED layout e_t[b][j][i][c].
// Round-8: k_evbn eliminated. For layers 1-3, edge_inner generates ev itself:
// stage BN(v[b]) as bf16 into the As LDS region (before e occupies it), MFMA
// against pre-transposed bf16 evWt -> output fragments ARE the evi[mt][nt]
// init values; ev_j extracted via __shfl from the owning lanes. v is
// ping-ponged (vA/vB) per layer because every block now reads ALL rows of
// v[b] while tails write their own 2 rows. Tail matvec keeps round-7's
// packed-bf16 2-way k-split form. 8 dispatches total.

typedef __bf16 bf16_t;
typedef __bf16 bf16x8 __attribute__((ext_vector_type(8)));
typedef __bf16 bf16x4 __attribute__((ext_vector_type(4)));
typedef __bf16 bf16x2 __attribute__((ext_vector_type(2)));
typedef float f32x4 __attribute__((ext_vector_type(4)));

__device__ __forceinline__ void bar_lgkm() {
  asm volatile("s_waitcnt lgkmcnt(0)\n\ts_barrier" ::: "memory");
}

__device__ __forceinline__ unsigned pack2(float a, float b) {
  bf16_t ba = (bf16_t)a, bb = (bf16_t)b;
  unsigned short ua, ub;
  __builtin_memcpy(&ua, &ba, 2);
  __builtin_memcpy(&ub, &bb, 2);
  return (unsigned)ua | ((unsigned)ub << 16);
}
__device__ __forceinline__ float blo(unsigned u) {
  unsigned v = u << 16; float f; __builtin_memcpy(&f, &v, 4); return f;
}
__device__ __forceinline__ float bhi(unsigned u) {
  unsigned v = u & 0xffff0000u; float f; __builtin_memcpy(&f, &v, 4); return f;
}

// ---------------- prep: input BN (v0), transposes, packed weights, zero stats ----------
__global__ __launch_bounds__(256) void k_prep(const float* __restrict__ vin,
    const float* __restrict__ g, const float* __restrict__ bt,
    const float* __restrict__ eW, const float* __restrict__ inn_vW,
    const float* __restrict__ g1_vW, const float* __restrict__ inn_evW,
    float* __restrict__ v0, bf16_t* __restrict__ Wt, float* __restrict__ stats,
    unsigned* __restrict__ vWp, unsigned* __restrict__ g1_vWp,
    unsigned* __restrict__ evWp, bf16_t* __restrict__ evWtB) {
  const int blk = blockIdx.x, tid = threadIdx.x;
  if (blk < 8) {  // BatchNorm1d(N*VF) over batch
    int ch = blk * 256 + tid;
    float s = 0.f, s2 = 0.f;
    for (int b = 0; b < 64; ++b) { float x = vin[b * 2048 + ch]; s += x; s2 += x * x; }
    float mu = s * (1.f / 64.f);
    float var = s2 * (1.f / 64.f) - mu * mu;
    float sc = rsqrtf(var + 1e-5f) * g[ch];
    float bb = bt[ch];
    for (int b = 0; b < 64; ++b) {
      float x = vin[b * 2048 + ch];
      v0[b * 2048 + ch] = (x - mu) * sc + bb;
    }
  } else if (blk < 264) {  // Wt[l][n][k] = eW[l][k][n] bf16 (edge MFMA A-frags)
    int idx = (blk - 8) * 256 + tid;
    int l = idx >> 14, r = idx & 16383, n = r >> 7, k = r & 127;
    Wt[idx] = (bf16_t)eW[(l << 14) + (k << 7) + n];
  } else if (blk == 264) {  // zero stats
    for (int i = tid; i < 512; i += 256) stats[i] = 0.f;
  } else if (blk < 521) {  // vWp: inn_vW [4][256][128] packed bf16 pairs
    int idx = (blk - 265) * 256 + tid;
    int l = idx >> 14, r = idx & 16383;
    int k8 = r >> 9, c = (r >> 2) & 127, j = r & 3;
    int ka = k8 * 8 + j * 2;
    vWp[idx] = pack2(inn_vW[(l << 15) + ka * 128 + c],
                     inn_vW[(l << 15) + (ka + 1) * 128 + c]);
  } else if (blk < 561) {  // g1_vWp: g1_vW [160][128] packed
    int idx = (blk - 521) * 256 + tid;
    int k8 = idx >> 9, c = (idx >> 2) & 127, j = idx & 3;
    int ka = k8 * 8 + j * 2;
    g1_vWp[idx] = pack2(g1_vW[ka * 128 + c], g1_vW[(ka + 1) * 128 + c]);
  } else if (blk < 689) {  // evWp: inn_evW [4][128][128] packed (g1 tail2 uses l=0)
    int idx = (blk - 561) * 256 + tid;
    int l = idx >> 13, r = idx & 8191;
    int k8 = r >> 9, c = (r >> 2) & 127, j = r & 3;
    int ka = k8 * 8 + j * 2;
    evWp[idx] = pack2(inn_evW[(l << 14) + ka * 128 + c],
                      inn_evW[(l << 14) + (ka + 1) * 128 + c]);
  } else {  // evWtB[l][n][k] = inn_evW[l][k][n] bf16 (ev MFMA A-frags)
    int idx = (blk - 689) * 256 + tid;  // 65536
    int l = idx >> 14, r = idx & 16383, n = r >> 7, k = r & 127;
    evWtB[idx] = (bf16_t)inn_evW[(l << 14) + (k << 7) + n];
  }
}

// ------------- ev = v_in @ W + bias : [4096,32]@[32,128] (g1 only). 8 rows/blk -------------
template <int K>
__global__ __launch_bounds__(256) void k_ev(const float* __restrict__ v_in,
    const float* __restrict__ W, const float* __restrict__ bias,
    float* __restrict__ out) {
  __shared__ float rows_s[8][K];
  const int r0 = blockIdx.x * 8;
  const int tid = threadIdx.x;
  const int c = tid & 127, h = tid >> 7;
  for (int idx = tid; idx < 8 * K; idx += 256) {
    int rr = idx / K, kk = idx % K;
    rows_s[rr][kk] = v_in[(r0 + rr) * K + kk];
  }
  __syncthreads();
  float acc[4];
  const float bv = bias[c];
#pragma unroll
  for (int r = 0; r < 4; ++r) acc[r] = bv;
  for (int k4 = 0; k4 < K; k4 += 4) {
    float w0 = W[(k4 + 0) * 128 + c], w1 = W[(k4 + 1) * 128 + c];
    float w2 = W[(k4 + 2) * 128 + c], w3 = W[(k4 + 3) * 128 + c];
#pragma unroll
    for (int r = 0; r < 4; ++r) {
      float4 x = *(const float4*)&rows_s[h * 4 + r][k4];
      acc[r] += x.x * w0 + x.y * w1 + x.z * w2 + x.w * w3;
    }
  }
#pragma unroll
  for (int r = 0; r < 4; ++r) out[(r0 + h * 4 + r) * 128 + c] = acc[r];
}

// ------------- g1 edge pass + fused g1-v + layer-0 ev (round-7 form, unchanged) ------
__global__ __launch_bounds__(256) void k_edge_g1(const float* __restrict__ e0,
    const float* __restrict__ eW, const float* __restrict__ eb,
    const float* __restrict__ evA, bf16_t* __restrict__ e_ws,
    const float* __restrict__ v0, const uint4* __restrict__ g1_vWp,
    const float* __restrict__ vb, const uint4* __restrict__ evW0p,
    const float* __restrict__ evb, float* __restrict__ v,
    float* __restrict__ evB) {
  __shared__ bf16_t A0s[2][64][40];
  __shared__ bf16_t Os[2][64][136];
  __shared__ float in_s[2][160];
  __shared__ float vr_s[2][128];
  __shared__ float red[2][2][128];
  const int b = blockIdx.x >> 5, j0 = (blockIdx.x & 31) * 2;
  const int tid = threadIdx.x;
  const int lane = tid & 63, w = tid >> 6;
  const int quad = lane >> 4, l16 = lane & 15;
  f32x4 v0reg;
  if (tid < 16)
    v0reg = *(const f32x4*)&v0[(b * 64 + j0 + (tid >> 3)) * 32 + (tid & 7) * 4];
#pragma unroll
  for (int t = 0; t < 2; ++t) {
    int idx = tid + t * 256;
    int row = idx >> 3, off = (idx & 7) * 4;
    int jc = off >> 4, k = off & 15;
    f32x4 x = *(const f32x4*)&e0[((b * 64 + row) * 64 + j0) * 16 + off];
    bf16x4 y;
#pragma unroll
    for (int r = 0; r < 4; ++r) y[r] = (bf16_t)x[r];
    *(bf16x4*)&A0s[jc][row][k] = y;
    bf16x4 z = {(bf16_t)0.f, (bf16_t)0.f, (bf16_t)0.f, (bf16_t)0.f};
    *(bf16x4*)&A0s[jc][row][16 + k] = z;
  }
  const int c0[2] = {w * 32 + quad * 4, w * 32 + 16 + quad * 4};
  bf16x8 wf[2];
#pragma unroll
  for (int nt = 0; nt < 2; ++nt) {
    const int c = w * 32 + nt * 16 + l16;
#pragma unroll
    for (int jj = 0; jj < 8; ++jj)
      wf[nt][jj] = (quad < 2) ? (bf16_t)eW[(quad * 8 + jj) * 128 + c] : (bf16_t)0.f;
  }
  f32x4 acc[2][4][2];
  {
    f32x4 ebv[2], evj[2][2], evi[4][2];
#pragma unroll
    for (int nt = 0; nt < 2; ++nt) {
      ebv[nt] = *(const f32x4*)&eb[c0[nt]];
#pragma unroll
      for (int jc = 0; jc < 2; ++jc)
        evj[jc][nt] = *(const f32x4*)&evA[(b * 64 + j0 + jc) * 128 + c0[nt]];
#pragma unroll
      for (int mt = 0; mt < 4; ++mt)
        evi[mt][nt] = *(const f32x4*)&evA[(b * 64 + mt * 16 + l16) * 128 + c0[nt]];
    }
#pragma unroll
    for (int jc = 0; jc < 2; ++jc)
#pragma unroll
      for (int mt = 0; mt < 4; ++mt)
#pragma unroll
        for (int nt = 0; nt < 2; ++nt)
          acc[jc][mt][nt] = ebv[nt] + evj[jc][nt] + evi[mt][nt];
  }
  __syncthreads();
#pragma unroll
  for (int jc = 0; jc < 2; ++jc) {
#pragma unroll
    for (int mt = 0; mt < 4; ++mt) {
      bf16x8 ef = *(const bf16x8*)&A0s[jc][mt * 16 + l16][quad * 8];
#pragma unroll
      for (int nt = 0; nt < 2; ++nt)
        acc[jc][mt][nt] = __builtin_amdgcn_mfma_f32_16x16x32_bf16(wf[nt], ef, acc[jc][mt][nt], 0, 0, 0);
    }
  }
#pragma unroll
  for (int jc = 0; jc < 2; ++jc) {
#pragma unroll
    for (int nt = 0; nt < 2; ++nt) {
      f32x4 ps = {0.f, 0.f, 0.f, 0.f};
#pragma unroll
      for (int mt = 0; mt < 4; ++mt) {
        const int i = mt * 16 + l16;
        bf16x4 outv;
#pragma unroll
        for (int r = 0; r < 4; ++r) {
          float vv = fmaxf(acc[jc][mt][nt][r], 0.f);
          ps[r] += vv;
          outv[r] = (bf16_t)vv;
        }
        *(bf16x4*)&Os[jc][i][c0[nt]] = outv;
      }
#pragma unroll
      for (int m = 1; m <= 8; m <<= 1) {
#pragma unroll
        for (int r = 0; r < 4; ++r) ps[r] += __shfl_xor(ps[r], m);
      }
      if (l16 == 0) *(f32x4*)&in_s[jc][c0[nt]] = ps;
    }
  }
  if (tid < 16) *(f32x4*)&in_s[tid >> 3][128 + (tid & 7) * 4] = v0reg;
  __syncthreads();
  {
    bf16_t* ebase = &e_ws[((size_t)(b * 64 + j0) * 64) * 128];
#pragma unroll
    for (int t = 0; t < 8; ++t) {
      int idx = tid + t * 256;
      *(int4*)&ebase[idx * 8] =
          *(const int4*)&Os[idx >> 10][(idx >> 4) & 63][(idx & 15) * 8];
    }
  }
  const int khalf = w >> 1, cbase = (w & 1) << 6;
  const int cc = cbase + lane;
  const int c = tid & 127, h = tid >> 7;
  {  // tail1: vr = relu(concat(pve,v0)@vW + vb); K=160
    float p0 = 0.f, p1 = 0.f;
    const uint4* Wp = &g1_vWp[(khalf * 10) * 128 + cc];
    const float* xs0 = &in_s[0][khalf * 80];
    const float* xs1 = &in_s[1][khalf * 80];
#pragma unroll 5
    for (int k8 = 0; k8 < 10; ++k8) {
      uint4 wv = Wp[k8 * 128];
      float we0 = blo(wv.x), wo0 = bhi(wv.x);
      float we1 = blo(wv.y), wo1 = bhi(wv.y);
      float we2 = blo(wv.z), wo2 = bhi(wv.z);
      float we3 = blo(wv.w), wo3 = bhi(wv.w);
      float4 xa0 = *(const float4*)&xs0[k8 * 8];
      float4 xb0 = *(const float4*)&xs0[k8 * 8 + 4];
      float4 xa1 = *(const float4*)&xs1[k8 * 8];
      float4 xb1 = *(const float4*)&xs1[k8 * 8 + 4];
      p0 += xa0.x * we0 + xa0.y * wo0 + xa0.z * we1 + xa0.w * wo1
          + xb0.x * we2 + xb0.y * wo2 + xb0.z * we3 + xb0.w * wo3;
      p1 += xa1.x * we0 + xa1.y * wo0 + xa1.z * we1 + xa1.w * wo1
          + xb1.x * we2 + xb1.y * wo2 + xb1.z * we3 + xb1.w * wo3;
    }
    red[khalf][0][cc] = p0;
    red[khalf][1][cc] = p1;
  }
  bar_lgkm();
  {
    float vacc = vb[c] + red[0][h][c] + red[1][h][c];
    float vr = fmaxf(vacc, 0.f);
    v[(b * 64 + j0 + h) * 128 + c] = vr;
    vr_s[h][c] = vr;
  }
  bar_lgkm();
  {  // tail2: evB = vr @ evW0 + evb; K=128
    float p0 = 0.f, p1 = 0.f;
    const uint4* Wp = &evW0p[(khalf * 8) * 128 + cc];
    const float* xs0 = &vr_s[0][khalf << 6];
    const float* xs1 = &vr_s[1][khalf << 6];
#pragma unroll 4
    for (int k8 = 0; k8 < 8; ++k8) {
      uint4 wv = Wp[k8 * 128];
      float we0 = blo(wv.x), wo0 = bhi(wv.x);
      float we1 = blo(wv.y), wo1 = bhi(wv.y);
      float we2 = blo(wv.z), wo2 = bhi(wv.z);
      float we3 = blo(wv.w), wo3 = bhi(wv.w);
      float4 xa0 = *(const float4*)&xs0[k8 * 8];
      float4 xb0 = *(const float4*)&xs0[k8 * 8 + 4];
      float4 xa1 = *(const float4*)&xs1[k8 * 8];
      float4 xb1 = *(const float4*)&xs1[k8 * 8 + 4];
      p0 += xa0.x * we0 + xa0.y * wo0 + xa0.z * we1 + xa0.w * wo1
          + xb0.x * we2 + xb0.y * wo2 + xb0.z * we3 + xb0.w * wo3;
      p1 += xa1.x * we0 + xa1.y * wo0 + xa1.z * we1 + xa1.w * wo1
          + xb1.x * we2 + xb1.y * wo2 + xb1.z * we3 + xb1.w * wo3;
    }
    red[khalf][0][cc] = p0;
    red[khalf][1][cc] = p1;
  }
  bar_lgkm();
  evB[(b * 64 + j0 + h) * 128 + c] = evb[c] + red[0][h][c] + red[1][h][c];
}

// ------------- inner edge pass + fused v-update & BN stats + (EVGEN) in-block ev -------
// EVGEN (layers 1-3): stage BN(vin[b]) bf16 into As[0], MFMA vs evWtB -> acc_ev
// fragments == evi layout; ev_j via __shfl. vin read-only, vout written (ping-pong).
// LAST: e write-back replaced by edot = dot(e_new, eW3).
template <bool LAST, bool EVGEN>
__global__ __launch_bounds__(256) void k_edge_inner(bf16_t* __restrict__ e_ws,
    const bf16_t* __restrict__ Wt, const float* __restrict__ eb,
    const float* __restrict__ ev, const float* __restrict__ eW3,
    float* __restrict__ edt, const float* __restrict__ vin,
    float* __restrict__ vout, const uint4* __restrict__ vWp,
    const float* __restrict__ vb, float* __restrict__ statsAcc,
    const float* __restrict__ statsPrev, const float* __restrict__ gPrev,
    const float* __restrict__ btPrev, const bf16_t* __restrict__ evWtB,
    const float* __restrict__ evb) {
  __shared__ bf16_t As[2][64][136];   // [jc][i][c], +8 pad; As[0] doubles as vbn stage
  __shared__ float W3s[128];
  __shared__ float in_s[2][256];      // [jc][ pve(128) | vbn_row(128) ]
  __shared__ float red[2][2][128];
  __shared__ float part[4][2];
  __shared__ float scs[64], shs[64];
  const int b = blockIdx.x >> 5, j0 = (blockIdx.x & 31) * 2;
  const int tid = threadIdx.x;
  const int lane = tid & 63, w = tid >> 6;
  const int quad = lane >> 4, l16 = lane & 15;
  bf16_t* ebase = &e_ws[((size_t)(b * 64 + j0) * 64) * 128];
  // e-tile loads issued first (latency hidden under everything below)
  int4 stg[8];
#pragma unroll
  for (int t = 0; t < 8; ++t) {
    int idx = tid + t * 256;
    stg[t] = *(const int4*)&ebase[idx * 8];
  }
  f32x4 vreg;
  if (tid < 64)
    vreg = *(const f32x4*)&vin[(b * 64 + j0 + (tid >> 5)) * 128 + (tid & 31) * 4];
  if (LAST) {
    if (tid < 128) W3s[tid] = eW3[tid];
  }
  bf16x8 wf[2][4];
#pragma unroll
  for (int nt = 0; nt < 2; ++nt)
#pragma unroll
    for (int ks = 0; ks < 4; ++ks)
      wf[nt][ks] = *(const bf16x8*)&Wt[(w * 32 + nt * 16 + l16) * 128 + ks * 32 + quad * 8];
  const int c0[2] = {w * 32 + quad * 4, w * 32 + 16 + quad * 4};
  f32x4 acc[2][4][2];
  if (EVGEN) {
    // -------- in-block ev: BN(vin[b]) @ evW + evb, via MFMA --------
    if (tid < 64) {
      float mu = statsPrev[tid] * (1.f / 8192.f);
      float var = statsPrev[64 + tid] * (1.f / 8192.f) - mu * mu;
      float sc = rsqrtf(var + 128.f) * gPrev[tid];
      scs[tid] = sc;
      shs[tid] = btPrev[tid] - mu * sc;
    }
    bf16x8 wf2[2][4];
#pragma unroll
    for (int nt = 0; nt < 2; ++nt)
#pragma unroll
      for (int ks = 0; ks < 4; ++ks)
        wf2[nt][ks] = *(const bf16x8*)&evWtB[(w * 32 + nt * 16 + l16) * 128 + ks * 32 + quad * 8];
    bar_lgkm();  // scs/shs ready
    // stage vbn = BN(vin[b]) as bf16 into As[0]; wave w handles rows t*4+w
#pragma unroll
    for (int t = 0; t < 16; ++t) {
      int row = t * 4 + w;
      float2 xv = *(const float2*)&vin[(b * 64 + row) * 128 + lane * 2];
      float sc = scs[row], sh = shs[row];
      bf16x2 o;
      o[0] = (bf16_t)(xv.x * sc + sh);
      o[1] = (bf16_t)(xv.y * sc + sh);
      *(bf16x2*)&As[0][row][lane * 2] = o;
    }
    if (tid < 64) {  // BN own rows for residual/concat
      int rr = j0 + (tid >> 5);
      vreg = vreg * scs[rr] + shs[rr];
    }
    bar_lgkm();  // vbn staged
    f32x4 acc_ev[4][2];
#pragma unroll
    for (int nt = 0; nt < 2; ++nt) {
      f32x4 bias = *(const f32x4*)&evb[c0[nt]];
#pragma unroll
      for (int mt = 0; mt < 4; ++mt) acc_ev[mt][nt] = bias;
    }
#pragma unroll
    for (int ks = 0; ks < 4; ++ks) {
      bf16x8 bfm[4];
#pragma unroll
      for (int mt = 0; mt < 4; ++mt)
        bfm[mt] = *(const bf16x8*)&As[0][mt * 16 + l16][ks * 32 + quad * 8];
#pragma unroll
      for (int mt = 0; mt < 4; ++mt)
#pragma unroll
        for (int nt = 0; nt < 2; ++nt)
          acc_ev[mt][nt] = __builtin_amdgcn_mfma_f32_16x16x32_bf16(wf2[nt][ks], bfm[mt], acc_ev[mt][nt], 0, 0, 0);
    }
    // ev_j extraction: rows j0,j0+1 live in tile mtj at l16=(j0+jc)&15, same quad
    const int mtj = j0 >> 4;
    f32x4 evrow[2];
#pragma unroll
    for (int mt = 0; mt < 4; ++mt)
      if (mtj == mt) { evrow[0] = acc_ev[mt][0]; evrow[1] = acc_ev[mt][1]; }
    f32x4 evj[2][2];
#pragma unroll
    for (int jc = 0; jc < 2; ++jc) {
      int src = (quad << 4) | ((j0 + jc) & 15);
#pragma unroll
      for (int nt = 0; nt < 2; ++nt)
#pragma unroll
        for (int r = 0; r < 4; ++r)
          evj[jc][nt][r] = __shfl(evrow[nt][r], src);
    }
#pragma unroll
    for (int nt = 0; nt < 2; ++nt) {
      f32x4 ebv = *(const f32x4*)&eb[c0[nt]];
#pragma unroll
      for (int jc = 0; jc < 2; ++jc)
#pragma unroll
        for (int mt = 0; mt < 4; ++mt)
          acc[jc][mt][nt] = ebv + evj[jc][nt] + acc_ev[mt][nt];
    }
    bar_lgkm();  // all waves done reading As[0] (vbn) before e overwrites it
  } else {
    f32x4 ebv[2], evj[2][2], evi[4][2];
#pragma unroll
    for (int nt = 0; nt < 2; ++nt) {
      ebv[nt] = *(const f32x4*)&eb[c0[nt]];
#pragma unroll
      for (int jc = 0; jc < 2; ++jc)
        evj[jc][nt] = *(const f32x4*)&ev[(b * 64 + j0 + jc) * 128 + c0[nt]];
#pragma unroll
      for (int mt = 0; mt < 4; ++mt)
        evi[mt][nt] = *(const f32x4*)&ev[(b * 64 + mt * 16 + l16) * 128 + c0[nt]];
    }
#pragma unroll
    for (int jc = 0; jc < 2; ++jc)
#pragma unroll
      for (int mt = 0; mt < 4; ++mt)
#pragma unroll
        for (int nt = 0; nt < 2; ++nt)
          acc[jc][mt][nt] = ebv[nt] + evj[jc][nt] + evi[mt][nt];
  }
  // stage e tile into As
#pragma unroll
  for (int t = 0; t < 8; ++t) {
    int idx = tid + t * 256;
    *(int4*)&As[idx >> 10][(idx >> 4) & 63][(idx & 15) * 8] = stg[t];
  }
  bar_lgkm();
  // edge MFMA: D[c][i] = sum_k Wt[c][k] * e[i][k]
#pragma unroll
  for (int ks = 0; ks < 4; ++ks) {
    bf16x8 ef[2][4];
#pragma unroll
    for (int jc = 0; jc < 2; ++jc)
#pragma unroll
      for (int mt = 0; mt < 4; ++mt)
        ef[jc][mt] = *(const bf16x8*)&As[jc][mt * 16 + l16][ks * 32 + quad * 8];
#pragma unroll
    for (int jc = 0; jc < 2; ++jc)
#pragma unroll
      for (int mt = 0; mt < 4; ++mt)
#pragma unroll
        for (int nt = 0; nt < 2; ++nt)
          acc[jc][mt][nt] = __builtin_amdgcn_mfma_f32_16x16x32_bf16(wf[nt][ks], ef[jc][mt], acc[jc][mt][nt], 0, 0, 0);
  }
  bar_lgkm();
  // epilogue: relu, pve->LDS, residual, write cells back to As
#pragma unroll
  for (int jc = 0; jc < 2; ++jc) {
#pragma unroll
    for (int nt = 0; nt < 2; ++nt) {
      f32x4 ps = {0.f, 0.f, 0.f, 0.f};
#pragma unroll
      for (int mt = 0; mt < 4; ++mt) {
        const int i = mt * 16 + l16;
        bf16x4 eo = *(const bf16x4*)&As[jc][i][c0[nt]];
        bf16x4 outv;
#pragma unroll
        for (int r = 0; r < 4; ++r) {
          float vv = fmaxf(acc[jc][mt][nt][r], 0.f);
          ps[r] += vv;
          outv[r] = (bf16_t)(vv + (float)eo[r]);
        }
        *(bf16x4*)&As[jc][i][c0[nt]] = outv;
      }
#pragma unroll
      for (int m = 1; m <= 8; m <<= 1) {
#pragma unroll
        for (int r = 0; r < 4; ++r) ps[r] += __shfl_xor(ps[r], m);
      }
      if (l16 == 0) *(f32x4*)&in_s[jc][c0[nt]] = ps;
    }
  }
  if (tid < 64) *(f32x4*)&in_s[tid >> 5][128 + (tid & 31) * 4] = vreg;
  bar_lgkm();
  // v-update tail partials (packed bf16 weights, 2-way k-split)
  const int khalf = w >> 1, cbase = (w & 1) << 6;
  const int cc = cbase + lane;
  float p0 = 0.f, p1 = 0.f;
  {
    const uint4* Wp = &vWp[(khalf * 16) * 128 + cc];
    const float* xs0 = &in_s[0][khalf << 7];
    const float* xs1 = &in_s[1][khalf << 7];
#pragma unroll 4
    for (int k8 = 0; k8 < 16; ++k8) {
      uint4 wv = Wp[k8 * 128];
      float we0 = blo(wv.x), wo0 = bhi(wv.x);
      float we1 = blo(wv.y), wo1 = bhi(wv.y);
      float we2 = blo(wv.z), wo2 = bhi(wv.z);
      float we3 = blo(wv.w), wo3 = bhi(wv.w);
      float4 xa0 = *(const float4*)&xs0[k8 * 8];
      float4 xb0 = *(const float4*)&xs0[k8 * 8 + 4];
      float4 xa1 = *(const float4*)&xs1[k8 * 8];
      float4 xb1 = *(const float4*)&xs1[k8 * 8 + 4];
      p0 += xa0.x * we0 + xa0.y * wo0 + xa0.z * we1 + xa0.w * wo1
          + xb0.x * we2 + xb0.y * wo2 + xb0.z * we3 + xb0.w * wo3;
      p1 += xa1.x * we0 + xa1.y * wo0 + xa1.z * we1 + xa1.w * wo1
          + xb1.x * we2 + xb1.y * wo2 + xb1.z * we3 + xb1.w * wo3;
    }
  }
  if (!LAST) {
#pragma unroll
    for (int t = 0; t < 8; ++t) {
      int idx = tid + t * 256;
      *(int4*)&ebase[idx * 8] =
          *(const int4*)&As[idx >> 10][(idx >> 4) & 63][(idx & 15) * 8];
    }
  } else {
    const int i = tid >> 2, q = tid & 3;
#pragma unroll
    for (int jc = 0; jc < 2; ++jc) {
      float d = 0.f;
#pragma unroll
      for (int t = 0; t < 4; ++t) {
        bf16x8 x = *(const bf16x8*)&As[jc][i][q * 32 + t * 8];
#pragma unroll
        for (int u = 0; u < 8; ++u) d += (float)x[u] * W3s[q * 32 + t * 8 + u];
      }
      d += __shfl_xor(d, 1);
      d += __shfl_xor(d, 2);
      if (q == 0) edt[(b * 64 + j0 + jc) * 64 + i] = d;
    }
  }
  red[khalf][0][cc] = p0;
  red[khalf][1][cc] = p1;
  bar_lgkm();
  const int c = tid & 127, h = tid >> 7;
  float vacc = vb[c] + red[0][h][c] + red[1][h][c];
  float vnew = fmaxf(vacc, 0.f) + in_s[h][128 + c];  // relu + residual (BN'd v)
  vout[(b * 64 + j0 + h) * 128 + c] = vnew;
  float s = vnew, s2 = vnew * vnew;
#pragma unroll
  for (int m = 1; m <= 32; m <<= 1) {
    s += __shfl_xor(s, m);
    s2 += __shfl_xor(s2, m);
  }
  if (lane == 0) { part[w][0] = s; part[w][1] = s2; }
  bar_lgkm();
  if (tid < 2) {
    int n = j0 + tid;
    atomicAdd(&statsAcc[n], part[tid * 2][0] + part[tid * 2 + 1][0]);
    atomicAdd(&statsAcc[64 + n], part[tid * 2][1] + part[tid * 2 + 1][1]);
  }
}

// ------------- g3 final (round-0 form, reads vA + stats[3]) -------------
__global__ __launch_bounds__(256) void k_g3(const float* __restrict__ vv,
    const float* __restrict__ stats3, const float* __restrict__ g,
    const float* __restrict__ bt, const float* __restrict__ evW3,
    const float* __restrict__ evb3, const float* __restrict__ eb3,
    const float* __restrict__ edt, const float* __restrict__ vW3,
    const float* __restrict__ vb3, float* __restrict__ out_v,
    float* __restrict__ out_e) {
  __shared__ float vbn[64][132];
  __shared__ float edts[64][68];
  __shared__ float scs[64], shs[64];
  __shared__ float W3e[128];
  __shared__ float vWs[132];
  __shared__ float ev3s[64];
  __shared__ float pj[4][64];
  const int b = blockIdx.x, tid = threadIdx.x;
  if (tid < 64) {
    float mu = stats3[tid] * (1.f / 8192.f);
    float var = stats3[64 + tid] * (1.f / 8192.f) - mu * mu;
    float sc = rsqrtf(var + 128.f) * g[tid];
    scs[tid] = sc;
    shs[tid] = bt[tid] - mu * sc;
  }
  if (tid < 128) W3e[tid] = evW3[tid];
  if (tid < 129) vWs[tid] = vW3[tid];
  __syncthreads();
#pragma unroll
  for (int t = 0; t < 8; ++t) {
    int idx = t * 1024 + tid * 4;
    int row = idx >> 7, cc = idx & 127;
    f32x4 x = *(const f32x4*)&vv[(b * 64 + row) * 128 + cc];
    *(f32x4*)&vbn[row][cc] = x * scs[row] + shs[row];
  }
#pragma unroll
  for (int t = 0; t < 4; ++t) {
    int idx = t * 1024 + tid * 4;
    int j = idx >> 6, i = idx & 63;
    *(f32x4*)&edts[j][i] = *(const f32x4*)&edt[(b * 64 + j) * 64 + i];
  }
  __syncthreads();
  {
    int i = tid >> 2, q = tid & 3;
    float d = 0.f;
#pragma unroll
    for (int u = 0; u < 32; ++u) d += vbn[i][q * 32 + u] * W3e[q * 32 + u];
    d += __shfl_xor(d, 1);
    d += __shfl_xor(d, 2);
    if (q == 0) ev3s[i] = d + evb3[0];
  }
  __syncthreads();
  {
    int q = tid >> 6, j = tid & 63;
    float s = 0.f;
    const float e3 = eb3[0];
    const float evj = ev3s[j];
#pragma unroll
    for (int r = 0; r < 16; ++r) {
      int i = q * 16 + r;
      float val = edts[j][i] + e3 + ev3s[i] + evj;
      out_e[(b * 64 + i) * 64 + j] = val;
      s += val;
    }
    pj[q][j] = s;
  }
  __syncthreads();
  {
    int n = tid >> 2, q = tid & 3;
    float d = 0.f;
#pragma unroll
    for (int u = 0; u < 32; ++u) d += vbn[n][q * 32 + u] * vWs[1 + q * 32 + u];
    d += __shfl_xor(d, 1);
    d += __shfl_xor(d, 2);
    if (q == 0) {
      float p3 = pj[0][n] + pj[1][n] + pj[2][n] + pj[3][n];
      out_v[b * 64 + n] = d + p3 * vWs[0] + vb3[0];
    }
  }
}

extern "C" void kernel_launch(void* const* d_in, const int* in_sizes, int n_in,
                              void* d_out, int out_size, void* d_ws, size_t ws_size,
                              hipStream_t stream) {
  const float* in_v    = (const float*)d_in[0];
  const float* in_e    = (const float*)d_in[1];
  const float* bn_in_g = (const float*)d_in[2];
  const float* bn_in_b = (const float*)d_in[3];
  const float* g1_evW  = (const float*)d_in[4];
  const float* g1_evb  = (const float*)d_in[5];
  const float* g1_eW   = (const float*)d_in[6];
  const float* g1_eb   = (const float*)d_in[7];
  const float* g1_vW   = (const float*)d_in[8];
  const float* g1_vb   = (const float*)d_in[9];
  const float* inn_evW = (const float*)d_in[10];
  const float* inn_evb = (const float*)d_in[11];
  const float* inn_eW  = (const float*)d_in[12];
  const float* inn_eb  = (const float*)d_in[13];
  const float* inn_vW  = (const float*)d_in[14];
  const float* inn_vb  = (const float*)d_in[15];
  const float* bn_g    = (const float*)d_in[16];
  const float* bn_b    = (const float*)d_in[17];
  const float* g3_evW  = (const float*)d_in[18];
  const float* g3_evb  = (const float*)d_in[19];
  const float* g3_eW   = (const float*)d_in[20];
  const float* g3_eb   = (const float*)d_in[21];
  const float* g3_vW   = (const float*)d_in[22];
  const float* g3_vb   = (const float*)d_in[23];

  char* ws = (char*)d_ws;
  bf16_t* e_ws = (bf16_t*)(ws);                       // 64MB
  float* vA       = (float*)(ws + 67108864);          // 2MB (v ping)
  float* evA      = (float*)(ws + 69206016);          // 2MB : g1's ev
  float* evB      = (float*)(ws + 71303168);          // 2MB : layer-0 ev
  float* v0       = (float*)(ws + 73400320);          // 512KB
  bf16_t* Wt      = (bf16_t*)(ws + 73924608);         // 128KB
  float* edt      = (float*)(ws + 74055680);          // 1MB
  float* stats    = (float*)(ws + 75104256);          // 2KB
  unsigned* vWp   = (unsigned*)(ws + 75106304);       // 256KB
  unsigned* g1_vWp= (unsigned*)(ws + 75368448);       // 40KB
  unsigned* evWp  = (unsigned*)(ws + 75409408);       // 128KB
  bf16_t* evWtB   = (bf16_t*)(ws + 75540480);         // 128KB
  float* vB       = (float*)(ws + 75671552);          // 2MB (v pong)

  float* out_v = (float*)d_out;
  float* out_e = (float*)d_out + 4096;

  k_prep<<<945, 256, 0, stream>>>(in_v, bn_in_g, bn_in_b, inn_eW, inn_vW, g1_vW,
                                  inn_evW, v0, Wt, stats, vWp, g1_vWp, evWp, evWtB);

  // ---- g1 (edge + fused v -> vA + fused layer-0 ev -> evB) ----
  k_ev<32><<<512, 256, 0, stream>>>(v0, g1_evW, g1_evb, evA);
  k_edge_g1<<<2048, 256, 0, stream>>>(in_e, g1_eW, g1_eb, evA, e_ws,
                                      v0, (const uint4*)g1_vWp, g1_vb,
                                      (const uint4*)evWp, inn_evb, vA, evB);

  // ---- inner layers (v ping-pong: l even reads vA->vB, l odd reads vB->vA) ----
  float* vbufs[2] = {vA, vB};
  for (int l = 0; l < 4; ++l) {
    float* vin_l  = vbufs[l & 1];
    float* vout_l = vbufs[(l + 1) & 1];
    if (l == 0)
      k_edge_inner<false, false><<<2048, 256, 0, stream>>>(e_ws, Wt,
          inn_eb, evB, g3_eW, edt, vin_l, vout_l,
          (const uint4*)vWp, inn_vb, stats,
          nullptr, nullptr, nullptr, nullptr, nullptr);
    else if (l < 3)
      k_edge_inner<false, true><<<2048, 256, 0, stream>>>(e_ws, Wt + l * 16384,
          inn_eb + l * 128, evB, g3_eW, edt, vin_l, vout_l,
          (const uint4*)vWp + l * 4096, inn_vb + l * 128, stats + l * 128,
          stats + (l - 1) * 128, bn_g + (l - 1) * 64, bn_b + (l - 1) * 64,
          evWtB + l * 16384, inn_evb + l * 128);
    else
      k_edge_inner<true, true><<<2048, 256, 0, stream>>>(e_ws, Wt + l * 16384,
          inn_eb + l * 128, evB, g3_eW, edt, vin_l, vout_l,
          (const uint4*)vWp + l * 4096, inn_vb + l * 128, stats + l * 128,
          stats + (l - 1) * 128, bn_g + (l - 1) * 64, bn_b + (l - 1) * 64,
          evWtB + l * 16384, inn_evb + l * 128);
  }

  // ---- g3 final (v after l=3 lands in vA; BN with stats[3] on the fly) ----
  k_g3<<<64, 256, 0, stream>>>(vA, stats + 384, bn_g + 192, bn_b + 192,
                               g3_evW, g3_evb, g3_eb, edt, g3_vW, g3_vb,
                               out_v, out_e);
}